// Round 1
// baseline (590.178 us; speedup 1.0000x reference)
//
#include <hip/hip_runtime.h>
#include <math.h>

#define N_NODES 8192
#define KNN 32

// ---------------------------------------------------------------------------
// Generic tiled fp32 GEMM: C[M x P] = A[M x K] @ W[K x P] + bias[P]
// Requirements: M % 64 == 0, K % 32 == 0, P % 4 == 0, pointers 16B aligned.
// 64x64 tile, 256 threads, 4x4 accum per thread, A staged transposed in LDS.
// ---------------------------------------------------------------------------
__global__ __launch_bounds__(256) void gemm_f32(
    const float* __restrict__ A, const float* __restrict__ W,
    const float* __restrict__ bias, float* __restrict__ C,
    int M, int K, int P)
{
    __shared__ float As[32][68];   // [k][m], padded (68*4B row, 16B-aligned)
    __shared__ float Ws[32][68];   // [k][n], padded

    const int tid  = threadIdx.x;
    const int row0 = blockIdx.x * 64;
    const int col0 = blockIdx.y * 64;
    const int ty = tid >> 4;       // 0..15
    const int tx = tid & 15;       // 0..15

    const int ar = tid >> 2;           // 0..63 (A row in tile)
    const int ak = (tid & 3) * 8;      // 0,8,16,24 (k offset)
    const int wk = tid >> 3;           // 0..31 (W k row)
    const int wc = (tid & 7) * 8;      // 0..56 (col offset)

    float acc[4][4];
#pragma unroll
    for (int i = 0; i < 4; ++i)
#pragma unroll
        for (int j = 0; j < 4; ++j) acc[i][j] = 0.0f;

    for (int k0 = 0; k0 < K; k0 += 32) {
        // --- stage A tile (transposed) ---
        const float* ap = A + (size_t)(row0 + ar) * K + (k0 + ak);
        float4 a0 = *(const float4*)(ap);
        float4 a1 = *(const float4*)(ap + 4);
        As[ak + 0][ar] = a0.x; As[ak + 1][ar] = a0.y;
        As[ak + 2][ar] = a0.z; As[ak + 3][ar] = a0.w;
        As[ak + 4][ar] = a1.x; As[ak + 5][ar] = a1.y;
        As[ak + 6][ar] = a1.z; As[ak + 7][ar] = a1.w;

        // --- stage W tile ---
        const int wcol = col0 + wc;
        float4 w0 = make_float4(0.f, 0.f, 0.f, 0.f);
        float4 w1 = make_float4(0.f, 0.f, 0.f, 0.f);
        const float* wp = W + (size_t)(k0 + wk) * P + wcol;
        if (wcol < P)     w0 = *(const float4*)(wp);
        if (wcol + 4 < P) w1 = *(const float4*)(wp + 4);
        *(float4*)&Ws[wk][wc]     = w0;
        *(float4*)&Ws[wk][wc + 4] = w1;

        __syncthreads();
#pragma unroll
        for (int kk = 0; kk < 32; ++kk) {
            float4 av = *(const float4*)&As[kk][ty * 4];
            float4 wv = *(const float4*)&Ws[kk][tx * 4];
            acc[0][0] += av.x * wv.x; acc[0][1] += av.x * wv.y;
            acc[0][2] += av.x * wv.z; acc[0][3] += av.x * wv.w;
            acc[1][0] += av.y * wv.x; acc[1][1] += av.y * wv.y;
            acc[1][2] += av.y * wv.z; acc[1][3] += av.y * wv.w;
            acc[2][0] += av.z * wv.x; acc[2][1] += av.z * wv.y;
            acc[2][2] += av.z * wv.z; acc[2][3] += av.z * wv.w;
            acc[3][0] += av.w * wv.x; acc[3][1] += av.w * wv.y;
            acc[3][2] += av.w * wv.z; acc[3][3] += av.w * wv.w;
        }
        __syncthreads();
    }

    const int col = col0 + tx * 4;
    if (col < P) {
        float4 b = *(const float4*)(bias + col);
#pragma unroll
        for (int i = 0; i < 4; ++i) {
            float4 o;
            o.x = acc[i][0] + b.x;
            o.y = acc[i][1] + b.y;
            o.z = acc[i][2] + b.z;
            o.w = acc[i][3] + b.w;
            *(float4*)(C + (size_t)(row0 + ty * 4 + i) * P + col) = o;
        }
    }
}

// ---------------------------------------------------------------------------
// Point-frame transform: raw (B,N,3,npts) -> pts (B,N,npts,3), y = R x + t
// q: npts=48 (H*PQ), kv: npts=144 (H*(PQ+PV))
// ---------------------------------------------------------------------------
__global__ void transform_pts(const float* __restrict__ qp_raw,
                              const float* __restrict__ kvp_raw,
                              const float* __restrict__ rot,
                              const float* __restrict__ trans,
                              float* __restrict__ q_pts,
                              float* __restrict__ kv_pts)
{
    int t = blockIdx.x * 256 + threadIdx.x;
    const int total = N_NODES * 192;   // 48 q-points + 144 kv-points per node
    if (t >= total) return;
    const int n = t / 192;
    const int m = t % 192;
    const float* R  = rot + n * 9;
    const float* tr = trans + n * 3;
    float X, Y, Z;
    float* dst;
    if (m < 48) {
        const float* src = qp_raw + (size_t)n * 144;
        X = src[m]; Y = src[48 + m]; Z = src[96 + m];
        dst = q_pts + (size_t)n * 144 + m * 3;
    } else {
        const int mm = m - 48;
        const float* src = kvp_raw + (size_t)n * 432;
        X = src[mm]; Y = src[144 + mm]; Z = src[288 + mm];
        dst = kv_pts + (size_t)n * 432 + mm * 3;
    }
    dst[0] = R[0] * X + R[1] * Y + R[2] * Z + tr[0];
    dst[1] = R[3] * X + R[4] * Y + R[5] * Z + tr[1];
    dst[2] = R[6] * X + R[7] * Y + R[8] * Z + tr[2];
}

// Concatenate w_b (128x12) | w_dz (128x32) -> Wcat (128x44), biases -> bcat(44)
__global__ void build_wcat(const float* __restrict__ wb, const float* __restrict__ bb,
                           const float* __restrict__ wdz, const float* __restrict__ bdz,
                           float* __restrict__ Wcat, float* __restrict__ bcat)
{
    int t = blockIdx.x * 256 + threadIdx.x;
    if (t < 128 * 44) {
        int c = t / 44, j = t % 44;
        Wcat[t] = (j < 12) ? wb[c * 12 + j] : wdz[c * 32 + (j - 12)];
    }
    if (t < 44) bcat[t] = (t < 12) ? bb[t] : bdz[t - 12];
}

// ---------------------------------------------------------------------------
// Per-node IPA attention. One block (256 threads) per node.
// q      : N x 192  (h*16+c)
// kv     : N x 384  (h*32 + [k:0..15 | v:16..31])
// q_pts  : N x 144  (h*12 + p*3 + x), global frame
// kv_pts : N x 432  (h*36 + pt*3 + x), pt<4 = k_pts, pt>=4 = v_pts
// zproj  : (N*K) x 44  (cols 0..11 = b_pair, 12..43 = pair_z)
// cat    : N x 960  [o(192) | o_pt.x(96) | o_pt.y(96) | o_pt.z(96) | norm(96) | o_pair(384)]
// ---------------------------------------------------------------------------
__global__ __launch_bounds__(256) void attn_kernel(
    const float* __restrict__ q,
    const float* __restrict__ kv,
    const float* __restrict__ q_pts,
    const float* __restrict__ kv_pts,
    const float* __restrict__ zproj,
    const int*   __restrict__ eidx,
    const float* __restrict__ mask,
    const float* __restrict__ rot,
    const float* __restrict__ trans,
    const float* __restrict__ head_weights,
    float* __restrict__ catb)
{
    const int n   = blockIdx.x;
    const int tid = threadIdx.x;

    __shared__ float q_s[192];
    __shared__ float qp_s[144];
    __shared__ float a_s[12][33];
    __shared__ int   idx_s[32];
    __shared__ float madd_s[32];
    __shared__ float R_s[9];
    __shared__ float t_s[3];
    __shared__ float hw_s[12];
    __shared__ float opt_s[12][8][3];

    for (int i = tid; i < 192; i += 256) q_s[i]  = q[(size_t)n * 192 + i];
    for (int i = tid; i < 144; i += 256) qp_s[i] = q_pts[(size_t)n * 144 + i];
    if (tid < 32)                 idx_s[tid]      = eidx[n * 32 + tid];
    if (tid >= 32 && tid < 41)    R_s[tid - 32]   = rot[n * 9 + (tid - 32)];
    if (tid >= 41 && tid < 44)    t_s[tid - 41]   = trans[n * 3 + (tid - 41)];
    if (tid >= 44 && tid < 56) {
        float x = head_weights[tid - 44];
        hw_s[tid - 44] = log1pf(__expf(x)) * 0.13608276348795434f; // softplus * sqrt(1/54)
    }
    __syncthreads();
    if (tid < 32) madd_s[tid] = 100000.0f * (mask[idx_s[tid]] - 1.0f);
    __syncthreads();

    // ---- logits: 384 (h,j) tasks ----
    for (int t = tid; t < 384; t += 256) {
        const int h = t >> 5, j = t & 31;
        const int idx = idx_s[j];
        const float* kr = kv + (size_t)idx * 384 + h * 32;
        float dot = 0.0f;
#pragma unroll
        for (int c = 0; c < 16; ++c) dot += q_s[h * 16 + c] * kr[c];
        const float* kp = kv_pts + (size_t)idx * 432 + h * 36;
        const float* qp = qp_s + h * 12;
        float pt = 0.0f;
#pragma unroll
        for (int e = 0; e < 12; ++e) { float d = qp[e] - kp[e]; pt += d * d; }
        float logit = 0.14433756729740643f * dot                       // 1/sqrt(3*C_H)
                    + 0.5773502691896258f * zproj[((size_t)n * 32 + j) * 44 + h]
                    - 0.5f * hw_s[h] * pt
                    + madd_s[j];
        a_s[h][j] = logit;
    }
    __syncthreads();

    // ---- softmax over j per head (12 serial rows; tiny) ----
    if (tid < 12) {
        float m = -1e30f;
#pragma unroll
        for (int j = 0; j < 32; ++j) m = fmaxf(m, a_s[tid][j]);
        float ssum = 0.0f;
#pragma unroll
        for (int j = 0; j < 32; ++j) {
            float e = __expf(a_s[tid][j] - m);
            a_s[tid][j] = e; ssum += e;
        }
        float inv = 1.0f / ssum;
#pragma unroll
        for (int j = 0; j < 32; ++j) a_s[tid][j] *= inv;
    }
    __syncthreads();

    // ---- weighted sums: o (192), o_pt raw (288), o_pair (384) ----
    float* catn = catb + (size_t)n * 960;
    for (int t = tid; t < 864; t += 256) {
        if (t < 192) {
            const int h = t >> 4, c = t & 15;
            float sacc = 0.0f;
#pragma unroll
            for (int j = 0; j < 32; ++j)
                sacc += a_s[h][j] * kv[(size_t)idx_s[j] * 384 + h * 32 + 16 + c];
            catn[h * 16 + c] = sacc;
        } else if (t < 480) {
            const int u = t - 192;               // 0..287
            const int h = u / 24, r = u % 24, p = r / 3, x = r % 3;
            float sacc = 0.0f;
#pragma unroll
            for (int j = 0; j < 32; ++j)
                sacc += a_s[h][j] * kv_pts[(size_t)idx_s[j] * 432 + h * 36 + (4 + p) * 3 + x];
            opt_s[h][p][x] = sacc;
        } else {
            const int u = t - 480;               // 0..383
            const int h = u >> 5, c = u & 31;
            float sacc = 0.0f;
#pragma unroll
            for (int j = 0; j < 32; ++j)
                sacc += a_s[h][j] * zproj[((size_t)n * 32 + j) * 44 + 12 + c];
            catn[576 + h * 32 + c] = sacc;
        }
    }
    __syncthreads();

    // ---- rotate back to local frame + norms ----
    if (tid < 96) {
        const int h = tid >> 3, p = tid & 7;
        float gx = opt_s[h][p][0] - t_s[0];
        float gy = opt_s[h][p][1] - t_s[1];
        float gz = opt_s[h][p][2] - t_s[2];
        float lx = R_s[0] * gx + R_s[3] * gy + R_s[6] * gz;  // R^T (x - t)
        float ly = R_s[1] * gx + R_s[4] * gy + R_s[7] * gz;
        float lz = R_s[2] * gx + R_s[5] * gy + R_s[8] * gz;
        const int hp = h * 8 + p;
        catn[192 + hp] = lx;
        catn[288 + hp] = ly;
        catn[384 + hp] = lz;
        catn[480 + hp] = sqrtf(lx * lx + ly * ly + lz * lz + 1e-8f);
    }
}

// ---------------------------------------------------------------------------
extern "C" void kernel_launch(void* const* d_in, const int* in_sizes, int n_in,
                              void* d_out, int out_size, void* d_ws, size_t ws_size,
                              hipStream_t stream)
{
    const float* s     = (const float*)d_in[0];
    const float* z     = (const float*)d_in[1];
    const int*   eidx  = (const int*)  d_in[2];
    const float* rot   = (const float*)d_in[3];
    const float* trans = (const float*)d_in[4];
    const float* mask  = (const float*)d_in[5];
    const float* w_q   = (const float*)d_in[6];
    const float* b_q   = (const float*)d_in[7];
    const float* w_kv  = (const float*)d_in[8];
    const float* b_kv  = (const float*)d_in[9];
    const float* w_qp  = (const float*)d_in[10];
    const float* b_qp  = (const float*)d_in[11];
    const float* w_kvp = (const float*)d_in[12];
    const float* b_kvp = (const float*)d_in[13];
    const float* w_b   = (const float*)d_in[14];
    const float* b_b   = (const float*)d_in[15];
    const float* w_dz  = (const float*)d_in[16];
    const float* b_dz  = (const float*)d_in[17];
    const float* hw    = (const float*)d_in[18];
    const float* w_out = (const float*)d_in[19];
    const float* b_out = (const float*)d_in[20];
    float* out = (float*)d_out;

    float* ws = (float*)d_ws;
    size_t off = 0;
    float* proj_q  = ws + off; off += (size_t)N_NODES * 192;
    float* proj_kv = ws + off; off += (size_t)N_NODES * 384;
    float* qp_raw  = ws + off; off += (size_t)N_NODES * 144;
    float* kvp_raw = ws + off; off += (size_t)N_NODES * 432;
    float* q_pts   = ws + off; off += (size_t)N_NODES * 144;
    float* kv_pts  = ws + off; off += (size_t)N_NODES * 432;
    float* zproj   = ws + off; off += (size_t)N_NODES * KNN * 44;
    float* catb    = ws + off; off += (size_t)N_NODES * 960;
    float* Wcat    = ws + off; off += 128 * 44;
    float* bcat    = ws + off; off += 44;

    // 1) scalar projections from s
    gemm_f32<<<dim3(N_NODES / 64, 3), 256, 0, stream>>>(s, w_q,   b_q,   proj_q,  N_NODES, 384, 192);
    gemm_f32<<<dim3(N_NODES / 64, 6), 256, 0, stream>>>(s, w_kv,  b_kv,  proj_kv, N_NODES, 384, 384);
    gemm_f32<<<dim3(N_NODES / 64, 3), 256, 0, stream>>>(s, w_qp,  b_qp,  qp_raw,  N_NODES, 384, 144);
    gemm_f32<<<dim3(N_NODES / 64, 7), 256, 0, stream>>>(s, w_kvp, b_kvp, kvp_raw, N_NODES, 384, 432);

    // 2) pair projections (one fused GEMM over concatenated weights)
    build_wcat<<<23, 256, 0, stream>>>(w_b, b_b, w_dz, b_dz, Wcat, bcat);
    gemm_f32<<<dim3((N_NODES * KNN) / 64, 1), 256, 0, stream>>>(z, Wcat, bcat, zproj,
                                                                N_NODES * KNN, 128, 44);

    // 3) transform points to global frame
    transform_pts<<<(N_NODES * 192 + 255) / 256, 256, 0, stream>>>(
        qp_raw, kvp_raw, rot, trans, q_pts, kv_pts);

    // 4) attention
    attn_kernel<<<N_NODES, 256, 0, stream>>>(
        proj_q, proj_kv, q_pts, kv_pts, zproj, eidx, mask, rot, trans, hw, catb);

    // 5) output projection
    gemm_f32<<<dim3(N_NODES / 64, 6), 256, 0, stream>>>(catb, w_out, b_out, out,
                                                        N_NODES, 960, 384);
}

// Round 2
// 396.201 us; speedup vs baseline: 1.4896x; 1.4896x over previous
//
#include <hip/hip_runtime.h>
#include <hip/hip_bf16.h>
#include <math.h>

#define N_NODES 8192
#define KNN 32

typedef unsigned short ushort_t;
typedef ushort_t ushort8 __attribute__((ext_vector_type(8)));

static __device__ __forceinline__ float b2f(ushort_t u) {
    union { float f; unsigned int i; } v; v.i = ((unsigned int)u) << 16; return v.f;
}
static __device__ __forceinline__ ushort_t f2b(float f) {
    __hip_bfloat16 h = __float2bfloat16(f);
    return *(ushort_t*)&h;
}

// ---------------------------------------------------------------------------
// Generic tiled fp32 GEMM: C[M x P] = A[M x K] @ W[K x P] + bias[P]
// M % 64 == 0, K % 32 == 0, P % 4 == 0.
// ---------------------------------------------------------------------------
__global__ __launch_bounds__(256) void gemm_f32(
    const float* __restrict__ A, const float* __restrict__ W,
    const float* __restrict__ bias, float* __restrict__ C,
    int M, int K, int P)
{
    __shared__ float As[32][68];
    __shared__ float Ws[32][68];

    const int tid  = threadIdx.x;
    const int row0 = blockIdx.x * 64;
    const int col0 = blockIdx.y * 64;
    const int ty = tid >> 4;
    const int tx = tid & 15;

    const int ar = tid >> 2;
    const int ak = (tid & 3) * 8;
    const int wk = tid >> 3;
    const int wc = (tid & 7) * 8;

    float acc[4][4];
#pragma unroll
    for (int i = 0; i < 4; ++i)
#pragma unroll
        for (int j = 0; j < 4; ++j) acc[i][j] = 0.0f;

    for (int k0 = 0; k0 < K; k0 += 32) {
        const float* ap = A + (size_t)(row0 + ar) * K + (k0 + ak);
        float4 a0 = *(const float4*)(ap);
        float4 a1 = *(const float4*)(ap + 4);
        As[ak + 0][ar] = a0.x; As[ak + 1][ar] = a0.y;
        As[ak + 2][ar] = a0.z; As[ak + 3][ar] = a0.w;
        As[ak + 4][ar] = a1.x; As[ak + 5][ar] = a1.y;
        As[ak + 6][ar] = a1.z; As[ak + 7][ar] = a1.w;

        const int wcol = col0 + wc;
        float4 w0 = make_float4(0.f, 0.f, 0.f, 0.f);
        float4 w1 = make_float4(0.f, 0.f, 0.f, 0.f);
        const float* wp = W + (size_t)(k0 + wk) * P + wcol;
        if (wcol < P)     w0 = *(const float4*)(wp);
        if (wcol + 4 < P) w1 = *(const float4*)(wp + 4);
        *(float4*)&Ws[wk][wc]     = w0;
        *(float4*)&Ws[wk][wc + 4] = w1;

        __syncthreads();
#pragma unroll
        for (int kk = 0; kk < 32; ++kk) {
            float4 av = *(const float4*)&As[kk][ty * 4];
            float4 wv = *(const float4*)&Ws[kk][tx * 4];
            acc[0][0] += av.x * wv.x; acc[0][1] += av.x * wv.y;
            acc[0][2] += av.x * wv.z; acc[0][3] += av.x * wv.w;
            acc[1][0] += av.y * wv.x; acc[1][1] += av.y * wv.y;
            acc[1][2] += av.y * wv.z; acc[1][3] += av.y * wv.w;
            acc[2][0] += av.z * wv.x; acc[2][1] += av.z * wv.y;
            acc[2][2] += av.z * wv.z; acc[2][3] += av.z * wv.w;
            acc[3][0] += av.w * wv.x; acc[3][1] += av.w * wv.y;
            acc[3][2] += av.w * wv.z; acc[3][3] += av.w * wv.w;
        }
        __syncthreads();
    }

    const int col = col0 + tx * 4;
    if (col < P) {
        float4 b = *(const float4*)(bias + col);
#pragma unroll
        for (int i = 0; i < 4; ++i) {
            float4 o;
            o.x = acc[i][0] + b.x;
            o.y = acc[i][1] + b.y;
            o.z = acc[i][2] + b.z;
            o.w = acc[i][3] + b.w;
            *(float4*)(C + (size_t)(row0 + ty * 4 + i) * P + col) = o;
        }
    }
}

// Build Wall (384 x 1152) = [w_q | w_kv | w_qp | w_kvp], ball(1152)
__global__ void build_wall(const float* __restrict__ wq,  const float* __restrict__ bq,
                           const float* __restrict__ wkv, const float* __restrict__ bkv,
                           const float* __restrict__ wqp, const float* __restrict__ bqp,
                           const float* __restrict__ wkvp,const float* __restrict__ bkvp,
                           float* __restrict__ Wall, float* __restrict__ ball)
{
    int t = blockIdx.x * 256 + threadIdx.x;
    if (t < 384 * 1152) {
        int c = t / 1152, j = t % 1152;
        float v;
        if      (j < 192)  v = wq  [c * 192 + j];
        else if (j < 576)  v = wkv [c * 384 + (j - 192)];
        else if (j < 720)  v = wqp [c * 144 + (j - 576)];
        else               v = wkvp[c * 432 + (j - 720)];
        Wall[t] = v;
    }
    if (t < 1152) {
        float v;
        if      (t < 192)  v = bq[t];
        else if (t < 576)  v = bkv[t - 192];
        else if (t < 720)  v = bqp[t - 576];
        else               v = bkvp[t - 720];
        ball[t] = v;
    }
}

// Concatenate w_b (128x12) | w_dz (128x32) -> Wcat (128x44)
__global__ void build_wcat(const float* __restrict__ wb, const float* __restrict__ bb,
                           const float* __restrict__ wdz, const float* __restrict__ bdz,
                           float* __restrict__ Wcat, float* __restrict__ bcat)
{
    int t = blockIdx.x * 256 + threadIdx.x;
    if (t < 128 * 44) {
        int c = t / 44, j = t % 44;
        Wcat[t] = (j < 12) ? wb[c * 12 + j] : wdz[c * 32 + (j - 12)];
    }
    if (t < 44) bcat[t] = (t < 12) ? bb[t] : bdz[t - 12];
}

// ---------------------------------------------------------------------------
// prep_tables: per node, 576 tasks
//   m <  48 : q point  (h*4+p)            -> q_pts fp32 [n][h*12+p*3+x]
//   m < 192 : kv point (h*12+p)           -> p<4: kpt fp32 [n][h*12+p*3+x]
//                                            p>=4: vpt bf16 [n][h*24+(p-4)*3+x]
//   m < 576 : kv scalar split/convert     -> kbt/vbt bf16 [n][h*16+c]
// proj_all row: [ q(0..191) | kv(192..575) | qp(576..719) | kvp(720..1151) ]
// ---------------------------------------------------------------------------
__global__ void prep_tables(const float* __restrict__ proj_all,
                            const float* __restrict__ rot,
                            const float* __restrict__ trans,
                            float* __restrict__ q_pts,
                            float* __restrict__ kpt,
                            ushort_t* __restrict__ vpt,
                            ushort_t* __restrict__ kbt,
                            ushort_t* __restrict__ vbt)
{
    int t = blockIdx.x * 256 + threadIdx.x;
    if (t >= N_NODES * 576) return;
    const int n = t / 576;
    const int m = t % 576;
    const float* row = proj_all + (size_t)n * 1152;

    if (m >= 192) {
        const int c0 = m - 192;
        const int h = c0 >> 5, c = c0 & 31;
        ushort_t v = f2b(row[192 + c0]);
        if (c < 16) kbt[(size_t)n * 192 + h * 16 + c] = v;
        else        vbt[(size_t)n * 192 + h * 16 + (c - 16)] = v;
        return;
    }

    const float* R  = rot + n * 9;
    const float* tr = trans + n * 3;
    float X, Y, Z;
    if (m < 48) {
        const float* src = row + 576;
        X = src[m]; Y = src[48 + m]; Z = src[96 + m];
        float gx = R[0] * X + R[1] * Y + R[2] * Z + tr[0];
        float gy = R[3] * X + R[4] * Y + R[5] * Z + tr[1];
        float gz = R[6] * X + R[7] * Y + R[8] * Z + tr[2];
        const int h = m >> 2, p = m & 3;
        float* dst = q_pts + (size_t)n * 144 + h * 12 + p * 3;
        dst[0] = gx; dst[1] = gy; dst[2] = gz;
    } else {
        const int pt = m - 48;            // 0..143
        const int h = pt / 12, p = pt % 12;
        const float* src = row + 720;
        X = src[pt]; Y = src[144 + pt]; Z = src[288 + pt];
        float gx = R[0] * X + R[1] * Y + R[2] * Z + tr[0];
        float gy = R[3] * X + R[4] * Y + R[5] * Z + tr[1];
        float gz = R[6] * X + R[7] * Y + R[8] * Z + tr[2];
        if (p < 4) {
            float* dst = kpt + (size_t)n * 144 + h * 12 + p * 3;
            dst[0] = gx; dst[1] = gy; dst[2] = gz;
        } else {
            ushort_t* dst = vpt + (size_t)n * 288 + h * 24 + (p - 4) * 3;
            dst[0] = f2b(gx); dst[1] = f2b(gy); dst[2] = f2b(gz);
        }
    }
}

// ---------------------------------------------------------------------------
// attention: one block (256 thr) per node; LDS-staged gather, two phases.
//   kbt/vbt : N x 192 bf16 (h*16+c)
//   kpt     : N x 144 fp32 (h*12+p*3+x)   global-frame k points
//   vpt     : N x 288 bf16 (h*24+p*3+x)   global-frame v points
//   zproj   : (N*K) x 44 fp32 (0..11 b_pair, 12..43 pair_z)
// LDS stage rows padded so 8-lane ds_read_b128 groups cover all 32 banks:
//   kb/vb row 200 ush (400B, mod128=16), kp row 148 f32 (592B, mod128=80),
//   vp row 296 ush (592B).
// ---------------------------------------------------------------------------
__global__ __launch_bounds__(256) void attn_kernel(
    const float* __restrict__ q,           // proj_all (row stride 1152, cols 0..191)
    const ushort_t* __restrict__ kbt,
    const ushort_t* __restrict__ vbt,
    const float* __restrict__ q_pts,
    const float* __restrict__ kpt,
    const ushort_t* __restrict__ vpt,
    const float* __restrict__ zproj,
    const int*   __restrict__ eidx,
    const float* __restrict__ mask,
    const float* __restrict__ rot,
    const float* __restrict__ trans,
    const float* __restrict__ head_weights,
    float* __restrict__ catb)
{
    const int n   = blockIdx.x;
    const int tid = threadIdx.x;

    __shared__ char __align__(16) stage_raw[31744];
    ushort_t (*kb)[200] = (ushort_t(*)[200])stage_raw;              // 12800B
    float    (*kp)[148] = (float(*)[148])(stage_raw + 12800);       // 18944B
    ushort_t (*vb)[200] = (ushort_t(*)[200])stage_raw;              // phase2 alias
    ushort_t (*vp)[296] = (ushort_t(*)[296])(stage_raw + 12800);

    __shared__ float q_s[192];
    __shared__ float qp_s[144];
    __shared__ float a_s[12][33];
    __shared__ int   idx_s[32];
    __shared__ float madd_s[32];
    __shared__ float R_s[9];
    __shared__ float t_s[3];
    __shared__ float hw_s[12];
    __shared__ float opt_s[12][8][3];

    // ---- seg0: node-local loads ----
    for (int i = tid; i < 192; i += 256) q_s[i]  = q[(size_t)n * 1152 + i];
    for (int i = tid; i < 144; i += 256) qp_s[i] = q_pts[(size_t)n * 144 + i];
    if (tid < 32)              idx_s[tid]     = eidx[n * 32 + tid];
    if (tid >= 32 && tid < 41) R_s[tid - 32]  = rot[n * 9 + (tid - 32)];
    if (tid >= 41 && tid < 44) t_s[tid - 41]  = trans[n * 3 + (tid - 41)];
    if (tid >= 44 && tid < 56) {
        float x = head_weights[tid - 44];
        hw_s[tid - 44] = log1pf(__expf(x)) * 0.13608276348795434f; // softplus*sqrt(1/54)
    }
    __syncthreads();

    // ---- seg1: mask + phase-1 staging (k rows bf16 + k_pts fp32) ----
    if (tid < 32) madd_s[tid] = 100000.0f * (mask[idx_s[tid]] - 1.0f);
    // kb: 32 rows x 24 x 16B chunks
    for (int c = tid; c < 768; c += 256) {
        const int r = c / 24, qc = c % 24;
        *(ushort8*)&kb[r][qc * 8] =
            *(const ushort8*)(kbt + (size_t)idx_s[r] * 192 + qc * 8);
    }
    // kp: 32 rows x 36 x 16B chunks
    for (int c = tid; c < 1152; c += 256) {
        const int r = c / 36, qc = c % 36;
        *(float4*)&kp[r][qc * 4] =
            *(const float4*)(kpt + (size_t)idx_s[r] * 144 + qc * 4);
    }
    __syncthreads();

    // ---- logits: 384 (h,j) tasks ----
    for (int t = tid; t < 384; t += 256) {
        const int h = t >> 5, j = t & 31;
        ushort8 k0 = *(const ushort8*)&kb[j][h * 16];
        ushort8 k1 = *(const ushort8*)&kb[j][h * 16 + 8];
        const float* qh = q_s + h * 16;
        float dot = 0.0f;
#pragma unroll
        for (int c = 0; c < 8; ++c) dot += qh[c] * b2f(k0[c]);
#pragma unroll
        for (int c = 0; c < 8; ++c) dot += qh[8 + c] * b2f(k1[c]);

        const float* kpr = &kp[j][h * 12];
        const float* qp  = qp_s + h * 12;
        float pt = 0.0f;
#pragma unroll
        for (int e = 0; e < 12; ++e) { float d = qp[e] - kpr[e]; pt += d * d; }

        float logit = 0.14433756729740643f * dot
                    + 0.5773502691896258f * zproj[((size_t)n * 32 + j) * 44 + h]
                    - 0.5f * hw_s[h] * pt
                    + madd_s[j];
        a_s[h][j] = logit;
    }
    __syncthreads();

    // ---- softmax (tid<12) overlapped with phase-2 staging (all threads) ----
    if (tid < 12) {
        float m = -1e30f;
#pragma unroll
        for (int j = 0; j < 32; ++j) m = fmaxf(m, a_s[tid][j]);
        float ssum = 0.0f;
#pragma unroll
        for (int j = 0; j < 32; ++j) {
            float e = __expf(a_s[tid][j] - m);
            a_s[tid][j] = e; ssum += e;
        }
        float inv = 1.0f / ssum;
#pragma unroll
        for (int j = 0; j < 32; ++j) a_s[tid][j] *= inv;
    }
    for (int c = tid; c < 768; c += 256) {
        const int r = c / 24, qc = c % 24;
        *(ushort8*)&vb[r][qc * 8] =
            *(const ushort8*)(vbt + (size_t)idx_s[r] * 192 + qc * 8);
    }
    for (int c = tid; c < 1152; c += 256) {
        const int r = c / 36, qc = c % 36;
        *(ushort8*)&vp[r][qc * 8] =
            *(const ushort8*)(vpt + (size_t)idx_s[r] * 288 + qc * 8);
    }
    __syncthreads();

    // ---- weighted sums: o(192) | o_pt(288) | o_pair(384) ----
    float* catn = catb + (size_t)n * 960;
    for (int t = tid; t < 864; t += 256) {
        if (t < 192) {
            const int h = t >> 4, c = t & 15;
            float sacc = 0.0f;
#pragma unroll
            for (int j = 0; j < 32; ++j)
                sacc += a_s[h][j] * b2f(vb[j][h * 16 + c]);
            catn[h * 16 + c] = sacc;
        } else if (t < 480) {
            const int u = t - 192;
            const int h = u / 24, r = u % 24, p = r / 3, x = r % 3;
            float sacc = 0.0f;
#pragma unroll
            for (int j = 0; j < 32; ++j)
                sacc += a_s[h][j] * b2f(vp[j][h * 24 + p * 3 + x]);
            opt_s[h][p][x] = sacc;
        } else {
            const int u = t - 480;
            const int h = u >> 5, c = u & 31;
            float sacc = 0.0f;
#pragma unroll
            for (int j = 0; j < 32; ++j)
                sacc += a_s[h][j] * zproj[((size_t)n * 32 + j) * 44 + 12 + c];
            catn[576 + h * 32 + c] = sacc;
        }
    }
    __syncthreads();

    // ---- rotate back + norms ----
    if (tid < 96) {
        const int h = tid >> 3, p = tid & 7;
        float gx = opt_s[h][p][0] - t_s[0];
        float gy = opt_s[h][p][1] - t_s[1];
        float gz = opt_s[h][p][2] - t_s[2];
        float lx = R_s[0] * gx + R_s[3] * gy + R_s[6] * gz;
        float ly = R_s[1] * gx + R_s[4] * gy + R_s[7] * gz;
        float lz = R_s[2] * gx + R_s[5] * gy + R_s[8] * gz;
        const int hp = h * 8 + p;
        catn[192 + hp] = lx;
        catn[288 + hp] = ly;
        catn[384 + hp] = lz;
        catn[480 + hp] = sqrtf(lx * lx + ly * ly + lz * lz + 1e-8f);
    }
}

// ---------------------------------------------------------------------------
extern "C" void kernel_launch(void* const* d_in, const int* in_sizes, int n_in,
                              void* d_out, int out_size, void* d_ws, size_t ws_size,
                              hipStream_t stream)
{
    const float* s     = (const float*)d_in[0];
    const float* z     = (const float*)d_in[1];
    const int*   eidx  = (const int*)  d_in[2];
    const float* rot   = (const float*)d_in[3];
    const float* trans = (const float*)d_in[4];
    const float* mask  = (const float*)d_in[5];
    const float* w_q   = (const float*)d_in[6];
    const float* b_q   = (const float*)d_in[7];
    const float* w_kv  = (const float*)d_in[8];
    const float* b_kv  = (const float*)d_in[9];
    const float* w_qp  = (const float*)d_in[10];
    const float* b_qp  = (const float*)d_in[11];
    const float* w_kvp = (const float*)d_in[12];
    const float* b_kvp = (const float*)d_in[13];
    const float* w_b   = (const float*)d_in[14];
    const float* b_b   = (const float*)d_in[15];
    const float* w_dz  = (const float*)d_in[16];
    const float* b_dz  = (const float*)d_in[17];
    const float* hw    = (const float*)d_in[18];
    const float* w_out = (const float*)d_in[19];
    const float* b_out = (const float*)d_in[20];
    float* out = (float*)d_out;

    float* ws = (float*)d_ws;
    size_t off = 0;
    float* proj_all = ws + off; off += (size_t)N_NODES * 1152;
    float* q_pts    = ws + off; off += (size_t)N_NODES * 144;
    float* kpt      = ws + off; off += (size_t)N_NODES * 144;
    ushort_t* vpt   = (ushort_t*)(ws + off); off += (size_t)N_NODES * 144;  // 288 bf16
    ushort_t* kbt   = (ushort_t*)(ws + off); off += (size_t)N_NODES * 96;   // 192 bf16
    ushort_t* vbt   = (ushort_t*)(ws + off); off += (size_t)N_NODES * 96;
    float* zproj    = ws + off; off += (size_t)N_NODES * KNN * 44;
    float* catb     = ws + off; off += (size_t)N_NODES * 960;
    float* Wall     = ws + off; off += (size_t)384 * 1152;
    float* ball     = ws + off; off += 1152;
    float* Wcat     = ws + off; off += 128 * 44;
    float* bcat     = ws + off; off += 44;

    // 1) fused s-projection (q|kv|qp|kvp)
    build_wall<<<(384 * 1152 + 255) / 256, 256, 0, stream>>>(
        w_q, b_q, w_kv, b_kv, w_qp, b_qp, w_kvp, b_kvp, Wall, ball);
    gemm_f32<<<dim3(N_NODES / 64, 18), 256, 0, stream>>>(s, Wall, ball, proj_all,
                                                         N_NODES, 384, 1152);

    // 2) pair projection (b_pair | pair_z fused)
    build_wcat<<<23, 256, 0, stream>>>(w_b, b_b, w_dz, b_dz, Wcat, bcat);
    gemm_f32<<<dim3((N_NODES * KNN) / 64, 1), 256, 0, stream>>>(z, Wcat, bcat, zproj,
                                                                N_NODES * KNN, 128, 44);

    // 3) gather tables: point transforms + bf16 conversions
    prep_tables<<<(N_NODES * 576 + 255) / 256, 256, 0, stream>>>(
        proj_all, rot, trans, q_pts, kpt, vpt, kbt, vbt);

    // 4) attention
    attn_kernel<<<N_NODES, 256, 0, stream>>>(
        proj_all, kbt, vbt, q_pts, kpt, vpt, zproj, eidx, mask, rot, trans, hw, catb);

    // 5) output projection
    gemm_f32<<<dim3(N_NODES / 64, 6), 256, 0, stream>>>(catb, w_out, b_out, out,
                                                        N_NODES, 960, 384);
}

// Round 3
// 282.331 us; speedup vs baseline: 2.0904x; 1.4033x over previous
//
#include <hip/hip_runtime.h>
#include <hip/hip_bf16.h>
#include <math.h>

#define N_NODES 8192
#define KNN 32

typedef unsigned short ushort_t;
typedef ushort_t ushort8 __attribute__((ext_vector_type(8)));
typedef short short8v __attribute__((ext_vector_type(8)));
typedef float f32x4 __attribute__((ext_vector_type(4)));

static __device__ __forceinline__ float b2f(ushort_t u) {
    union { float f; unsigned int i; } v; v.i = ((unsigned int)u) << 16; return v.f;
}
static __device__ __forceinline__ ushort_t f2b(float f) {
    __hip_bfloat16 h = __float2bfloat16(f);
    return *(ushort_t*)&h;
}

// ---------------------------------------------------------------------------
// bf16 MFMA GEMM: C[M x P] = A[M x K] @ W[K x P] + bias[P]  (fp32 in/out,
// bf16 conversion fused into LDS staging). M%128==0, K%32==0, any P%4==0.
// 256 thr = 4 waves; wave (wm,wn) computes 64x64 via 4x4 frags of 16x16x32.
// LDS rows padded to 40 ushorts (80B): b128 frag reads are 2-way (free).
// ---------------------------------------------------------------------------
__global__ __launch_bounds__(256) void gemm_bf16(
    const float* __restrict__ A, const float* __restrict__ W,
    const float* __restrict__ bias, float* __restrict__ C,
    int M, int K, int P)
{
    __shared__ ushort_t As[128][40];   // [m][k]
    __shared__ ushort_t Bs[128][40];   // [n][k]  (transposed)

    const int tid  = threadIdx.x;
    const int row0 = blockIdx.x * 128;
    const int col0 = blockIdx.y * 128;

    const int wave = tid >> 6;
    const int lane = tid & 63;
    const int wm = (wave >> 1) * 64;
    const int wn = (wave & 1) * 64;
    const int m16 = lane & 15;
    const int kof = (lane >> 4) * 8;

    // A staging map: 128 rows x 32 k / 256 thr -> 16 floats each
    const int a_row = tid >> 1;
    const int a_kq  = (tid & 1) * 16;
    // B staging map: thread owns one n-col, 16 k values
    const int b_n  = tid >> 1;          // 0..127
    const int b_kq = (tid & 1) * 16;

    f32x4 acc[4][4];
#pragma unroll
    for (int i = 0; i < 4; ++i)
#pragma unroll
        for (int j = 0; j < 4; ++j) acc[i][j] = (f32x4)0.0f;

    for (int k0 = 0; k0 < K; k0 += 32) {
        // ---- stage A (fp32 -> bf16) ----
        {
            const float* ap = A + (size_t)(row0 + a_row) * K + (k0 + a_kq);
            float4 v0 = *(const float4*)(ap);
            float4 v1 = *(const float4*)(ap + 4);
            float4 v2 = *(const float4*)(ap + 8);
            float4 v3 = *(const float4*)(ap + 12);
            ushort8 u0, u1;
            u0[0] = f2b(v0.x); u0[1] = f2b(v0.y); u0[2] = f2b(v0.z); u0[3] = f2b(v0.w);
            u0[4] = f2b(v1.x); u0[5] = f2b(v1.y); u0[6] = f2b(v1.z); u0[7] = f2b(v1.w);
            u1[0] = f2b(v2.x); u1[1] = f2b(v2.y); u1[2] = f2b(v2.z); u1[3] = f2b(v2.w);
            u1[4] = f2b(v3.x); u1[5] = f2b(v3.y); u1[6] = f2b(v3.z); u1[7] = f2b(v3.w);
            *(ushort8*)&As[a_row][a_kq]     = u0;
            *(ushort8*)&As[a_row][a_kq + 8] = u1;
        }
        // ---- stage B transposed (coalesced k-strided loads) ----
        {
            const int col = col0 + b_n;
            ushort8 u0, u1;
            if (col < P) {
                const float* wp = W + (size_t)(k0 + b_kq) * P + col;
#pragma unroll
                for (int i = 0; i < 8; ++i) { u0[i] = f2b(*wp); wp += P; }
#pragma unroll
                for (int i = 0; i < 8; ++i) { u1[i] = f2b(*wp); wp += P; }
            } else {
                u0 = (ushort8)0; u1 = (ushort8)0;
            }
            *(ushort8*)&Bs[b_n][b_kq]     = u0;
            *(ushort8*)&Bs[b_n][b_kq + 8] = u1;
        }
        __syncthreads();

        short8v a[4], b[4];
#pragma unroll
        for (int mb = 0; mb < 4; ++mb)
            a[mb] = *(const short8v*)&As[wm + mb * 16 + m16][kof];
#pragma unroll
        for (int nb = 0; nb < 4; ++nb)
            b[nb] = *(const short8v*)&Bs[wn + nb * 16 + m16][kof];
#pragma unroll
        for (int mb = 0; mb < 4; ++mb)
#pragma unroll
            for (int nb = 0; nb < 4; ++nb)
                acc[mb][nb] = __builtin_amdgcn_mfma_f32_16x16x32_bf16(
                    a[mb], b[nb], acc[mb][nb], 0, 0, 0);
        __syncthreads();
    }

    // ---- epilogue ----
    const int r_base = row0 + wm + (lane >> 4) * 4;
#pragma unroll
    for (int nb = 0; nb < 4; ++nb) {
        const int col = col0 + wn + nb * 16 + m16;
        if (col >= P) continue;
        const float bv = bias[col];
#pragma unroll
        for (int mb = 0; mb < 4; ++mb) {
#pragma unroll
            for (int r = 0; r < 4; ++r) {
                C[(size_t)(r_base + mb * 16 + r) * P + col] = acc[mb][nb][r] + bv;
            }
        }
    }
}

// Build Wall (384 x 1152) = [w_q | w_kv | w_qp | w_kvp], ball(1152)
__global__ void build_wall(const float* __restrict__ wq,  const float* __restrict__ bq,
                           const float* __restrict__ wkv, const float* __restrict__ bkv,
                           const float* __restrict__ wqp, const float* __restrict__ bqp,
                           const float* __restrict__ wkvp,const float* __restrict__ bkvp,
                           float* __restrict__ Wall, float* __restrict__ ball)
{
    int t = blockIdx.x * 256 + threadIdx.x;
    if (t < 384 * 1152) {
        int c = t / 1152, j = t % 1152;
        float v;
        if      (j < 192)  v = wq  [c * 192 + j];
        else if (j < 576)  v = wkv [c * 384 + (j - 192)];
        else if (j < 720)  v = wqp [c * 144 + (j - 576)];
        else               v = wkvp[c * 432 + (j - 720)];
        Wall[t] = v;
    }
    if (t < 1152) {
        float v;
        if      (t < 192)  v = bq[t];
        else if (t < 576)  v = bkv[t - 192];
        else if (t < 720)  v = bqp[t - 576];
        else               v = bkvp[t - 720];
        ball[t] = v;
    }
}

// Concatenate w_b (128x12) | w_dz (128x32) -> Wcat (128x44)
__global__ void build_wcat(const float* __restrict__ wb, const float* __restrict__ bb,
                           const float* __restrict__ wdz, const float* __restrict__ bdz,
                           float* __restrict__ Wcat, float* __restrict__ bcat)
{
    int t = blockIdx.x * 256 + threadIdx.x;
    if (t < 128 * 44) {
        int c = t / 44, j = t % 44;
        Wcat[t] = (j < 12) ? wb[c * 12 + j] : wdz[c * 32 + (j - 12)];
    }
    if (t < 44) bcat[t] = (t < 12) ? bb[t] : bdz[t - 12];
}

// ---------------------------------------------------------------------------
// prep_tables: per node, 576 tasks (see round-1 comments)
// ---------------------------------------------------------------------------
__global__ void prep_tables(const float* __restrict__ proj_all,
                            const float* __restrict__ rot,
                            const float* __restrict__ trans,
                            float* __restrict__ q_pts,
                            float* __restrict__ kpt,
                            ushort_t* __restrict__ vpt,
                            ushort_t* __restrict__ kbt,
                            ushort_t* __restrict__ vbt)
{
    int t = blockIdx.x * 256 + threadIdx.x;
    if (t >= N_NODES * 576) return;
    const int n = t / 576;
    const int m = t % 576;
    const float* row = proj_all + (size_t)n * 1152;

    if (m >= 192) {
        const int c0 = m - 192;
        const int h = c0 >> 5, c = c0 & 31;
        ushort_t v = f2b(row[192 + c0]);
        if (c < 16) kbt[(size_t)n * 192 + h * 16 + c] = v;
        else        vbt[(size_t)n * 192 + h * 16 + (c - 16)] = v;
        return;
    }

    const float* R  = rot + n * 9;
    const float* tr = trans + n * 3;
    float X, Y, Z;
    if (m < 48) {
        const float* src = row + 576;
        X = src[m]; Y = src[48 + m]; Z = src[96 + m];
        float gx = R[0] * X + R[1] * Y + R[2] * Z + tr[0];
        float gy = R[3] * X + R[4] * Y + R[5] * Z + tr[1];
        float gz = R[6] * X + R[7] * Y + R[8] * Z + tr[2];
        const int h = m >> 2, p = m & 3;
        float* dst = q_pts + (size_t)n * 144 + h * 12 + p * 3;
        dst[0] = gx; dst[1] = gy; dst[2] = gz;
    } else {
        const int pt = m - 48;
        const int h = pt / 12, p = pt % 12;
        const float* src = row + 720;
        X = src[pt]; Y = src[144 + pt]; Z = src[288 + pt];
        float gx = R[0] * X + R[1] * Y + R[2] * Z + tr[0];
        float gy = R[3] * X + R[4] * Y + R[5] * Z + tr[1];
        float gz = R[6] * X + R[7] * Y + R[8] * Z + tr[2];
        if (p < 4) {
            float* dst = kpt + (size_t)n * 144 + h * 12 + p * 3;
            dst[0] = gx; dst[1] = gy; dst[2] = gz;
        } else {
            ushort_t* dst = vpt + (size_t)n * 288 + h * 24 + (p - 4) * 3;
            dst[0] = f2b(gx); dst[1] = f2b(gy); dst[2] = f2b(gz);
        }
    }
}

// ---------------------------------------------------------------------------
// attention (unchanged from round 1): one block (256 thr) per node.
// ---------------------------------------------------------------------------
__global__ __launch_bounds__(256) void attn_kernel(
    const float* __restrict__ q,
    const ushort_t* __restrict__ kbt,
    const ushort_t* __restrict__ vbt,
    const float* __restrict__ q_pts,
    const float* __restrict__ kpt,
    const ushort_t* __restrict__ vpt,
    const float* __restrict__ zproj,
    const int*   __restrict__ eidx,
    const float* __restrict__ mask,
    const float* __restrict__ rot,
    const float* __restrict__ trans,
    const float* __restrict__ head_weights,
    float* __restrict__ catb)
{
    const int n   = blockIdx.x;
    const int tid = threadIdx.x;

    __shared__ char __align__(16) stage_raw[31744];
    ushort_t (*kb)[200] = (ushort_t(*)[200])stage_raw;
    float    (*kp)[148] = (float(*)[148])(stage_raw + 12800);
    ushort_t (*vb)[200] = (ushort_t(*)[200])stage_raw;
    ushort_t (*vp)[296] = (ushort_t(*)[296])(stage_raw + 12800);

    __shared__ float q_s[192];
    __shared__ float qp_s[144];
    __shared__ float a_s[12][33];
    __shared__ int   idx_s[32];
    __shared__ float madd_s[32];
    __shared__ float R_s[9];
    __shared__ float t_s[3];
    __shared__ float hw_s[12];
    __shared__ float opt_s[12][8][3];

    for (int i = tid; i < 192; i += 256) q_s[i]  = q[(size_t)n * 1152 + i];
    for (int i = tid; i < 144; i += 256) qp_s[i] = q_pts[(size_t)n * 144 + i];
    if (tid < 32)              idx_s[tid]     = eidx[n * 32 + tid];
    if (tid >= 32 && tid < 41) R_s[tid - 32]  = rot[n * 9 + (tid - 32)];
    if (tid >= 41 && tid < 44) t_s[tid - 41]  = trans[n * 3 + (tid - 41)];
    if (tid >= 44 && tid < 56) {
        float x = head_weights[tid - 44];
        hw_s[tid - 44] = log1pf(__expf(x)) * 0.13608276348795434f;
    }
    __syncthreads();

    if (tid < 32) madd_s[tid] = 100000.0f * (mask[idx_s[tid]] - 1.0f);
    for (int c = tid; c < 768; c += 256) {
        const int r = c / 24, qc = c % 24;
        *(ushort8*)&kb[r][qc * 8] =
            *(const ushort8*)(kbt + (size_t)idx_s[r] * 192 + qc * 8);
    }
    for (int c = tid; c < 1152; c += 256) {
        const int r = c / 36, qc = c % 36;
        *(float4*)&kp[r][qc * 4] =
            *(const float4*)(kpt + (size_t)idx_s[r] * 144 + qc * 4);
    }
    __syncthreads();

    for (int t = tid; t < 384; t += 256) {
        const int h = t >> 5, j = t & 31;
        ushort8 k0 = *(const ushort8*)&kb[j][h * 16];
        ushort8 k1 = *(const ushort8*)&kb[j][h * 16 + 8];
        const float* qh = q_s + h * 16;
        float dot = 0.0f;
#pragma unroll
        for (int c = 0; c < 8; ++c) dot += qh[c] * b2f(k0[c]);
#pragma unroll
        for (int c = 0; c < 8; ++c) dot += qh[8 + c] * b2f(k1[c]);

        const float* kpr = &kp[j][h * 12];
        const float* qp  = qp_s + h * 12;
        float pt = 0.0f;
#pragma unroll
        for (int e = 0; e < 12; ++e) { float d = qp[e] - kpr[e]; pt += d * d; }

        float logit = 0.14433756729740643f * dot
                    + 0.5773502691896258f * zproj[((size_t)n * 32 + j) * 44 + h]
                    - 0.5f * hw_s[h] * pt
                    + madd_s[j];
        a_s[h][j] = logit;
    }
    __syncthreads();

    if (tid < 12) {
        float m = -1e30f;
#pragma unroll
        for (int j = 0; j < 32; ++j) m = fmaxf(m, a_s[tid][j]);
        float ssum = 0.0f;
#pragma unroll
        for (int j = 0; j < 32; ++j) {
            float e = __expf(a_s[tid][j] - m);
            a_s[tid][j] = e; ssum += e;
        }
        float inv = 1.0f / ssum;
#pragma unroll
        for (int j = 0; j < 32; ++j) a_s[tid][j] *= inv;
    }
    for (int c = tid; c < 768; c += 256) {
        const int r = c / 24, qc = c % 24;
        *(ushort8*)&vb[r][qc * 8] =
            *(const ushort8*)(vbt + (size_t)idx_s[r] * 192 + qc * 8);
    }
    for (int c = tid; c < 1152; c += 256) {
        const int r = c / 36, qc = c % 36;
        *(ushort8*)&vp[r][qc * 8] =
            *(const ushort8*)(vpt + (size_t)idx_s[r] * 288 + qc * 8);
    }
    __syncthreads();

    float* catn = catb + (size_t)n * 960;
    for (int t = tid; t < 864; t += 256) {
        if (t < 192) {
            const int h = t >> 4, c = t & 15;
            float sacc = 0.0f;
#pragma unroll
            for (int j = 0; j < 32; ++j)
                sacc += a_s[h][j] * b2f(vb[j][h * 16 + c]);
            catn[h * 16 + c] = sacc;
        } else if (t < 480) {
            const int u = t - 192;
            const int h = u / 24, r = u % 24, p = r / 3, x = r % 3;
            float sacc = 0.0f;
#pragma unroll
            for (int j = 0; j < 32; ++j)
                sacc += a_s[h][j] * b2f(vp[j][h * 24 + p * 3 + x]);
            opt_s[h][p][x] = sacc;
        } else {
            const int u = t - 480;
            const int h = u >> 5, c = u & 31;
            float sacc = 0.0f;
#pragma unroll
            for (int j = 0; j < 32; ++j)
                sacc += a_s[h][j] * zproj[((size_t)n * 32 + j) * 44 + 12 + c];
            catn[576 + h * 32 + c] = sacc;
        }
    }
    __syncthreads();

    if (tid < 96) {
        const int h = tid >> 3, p = tid & 7;
        float gx = opt_s[h][p][0] - t_s[0];
        float gy = opt_s[h][p][1] - t_s[1];
        float gz = opt_s[h][p][2] - t_s[2];
        float lx = R_s[0] * gx + R_s[3] * gy + R_s[6] * gz;
        float ly = R_s[1] * gx + R_s[4] * gy + R_s[7] * gz;
        float lz = R_s[2] * gx + R_s[5] * gy + R_s[8] * gz;
        const int hp = h * 8 + p;
        catn[192 + hp] = lx;
        catn[288 + hp] = ly;
        catn[384 + hp] = lz;
        catn[480 + hp] = sqrtf(lx * lx + ly * ly + lz * lz + 1e-8f);
    }
}

// ---------------------------------------------------------------------------
extern "C" void kernel_launch(void* const* d_in, const int* in_sizes, int n_in,
                              void* d_out, int out_size, void* d_ws, size_t ws_size,
                              hipStream_t stream)
{
    const float* s     = (const float*)d_in[0];
    const float* z     = (const float*)d_in[1];
    const int*   eidx  = (const int*)  d_in[2];
    const float* rot   = (const float*)d_in[3];
    const float* trans = (const float*)d_in[4];
    const float* mask  = (const float*)d_in[5];
    const float* w_q   = (const float*)d_in[6];
    const float* b_q   = (const float*)d_in[7];
    const float* w_kv  = (const float*)d_in[8];
    const float* b_kv  = (const float*)d_in[9];
    const float* w_qp  = (const float*)d_in[10];
    const float* b_qp  = (const float*)d_in[11];
    const float* w_kvp = (const float*)d_in[12];
    const float* b_kvp = (const float*)d_in[13];
    const float* w_b   = (const float*)d_in[14];
    const float* b_b   = (const float*)d_in[15];
    const float* w_dz  = (const float*)d_in[16];
    const float* b_dz  = (const float*)d_in[17];
    const float* hw    = (const float*)d_in[18];
    const float* w_out = (const float*)d_in[19];
    const float* b_out = (const float*)d_in[20];
    float* out = (float*)d_out;

    float* ws = (float*)d_ws;
    size_t off = 0;
    float* proj_all = ws + off; off += (size_t)N_NODES * 1152;
    float* q_pts    = ws + off; off += (size_t)N_NODES * 144;
    float* kpt      = ws + off; off += (size_t)N_NODES * 144;
    ushort_t* vpt   = (ushort_t*)(ws + off); off += (size_t)N_NODES * 144;
    ushort_t* kbt   = (ushort_t*)(ws + off); off += (size_t)N_NODES * 96;
    ushort_t* vbt   = (ushort_t*)(ws + off); off += (size_t)N_NODES * 96;
    float* zproj    = ws + off; off += (size_t)N_NODES * KNN * 44;
    float* catb     = ws + off; off += (size_t)N_NODES * 960;
    float* Wall     = ws + off; off += (size_t)384 * 1152;
    float* ball     = ws + off; off += 1152;
    float* Wcat     = ws + off; off += 128 * 44;
    float* bcat     = ws + off; off += 44;

    // 1) fused s-projection (q|kv|qp|kvp) via MFMA
    build_wall<<<(384 * 1152 + 255) / 256, 256, 0, stream>>>(
        w_q, b_q, w_kv, b_kv, w_qp, b_qp, w_kvp, b_kvp, Wall, ball);
    gemm_bf16<<<dim3(N_NODES / 128, 9), 256, 0, stream>>>(s, Wall, ball, proj_all,
                                                          N_NODES, 384, 1152);

    // 2) pair projection via MFMA (P=44 masked inside 128-tile)
    build_wcat<<<23, 256, 0, stream>>>(w_b, b_b, w_dz, b_dz, Wcat, bcat);
    gemm_bf16<<<dim3((N_NODES * KNN) / 128, 1), 256, 0, stream>>>(z, Wcat, bcat, zproj,
                                                                  N_NODES * KNN, 128, 44);

    // 3) gather tables: point transforms + bf16 conversions
    prep_tables<<<(N_NODES * 576 + 255) / 256, 256, 0, stream>>>(
        proj_all, rot, trans, q_pts, kpt, vpt, kbt, vbt);

    // 4) attention
    attn_kernel<<<N_NODES, 256, 0, stream>>>(
        proj_all, kbt, vbt, q_pts, kpt, vpt, zproj, eidx, mask, rot, trans, hw, catb);

    // 5) output projection via MFMA
    gemm_bf16<<<dim3(N_NODES / 128, 3), 256, 0, stream>>>(catb, w_out, b_out, out,
                                                          N_NODES, 960, 384);
}

// Round 4
// 269.206 us; speedup vs baseline: 2.1923x; 1.0488x over previous
//
#include <hip/hip_runtime.h>
#include <hip/hip_bf16.h>
#include <math.h>

#define N_NODES 8192
#define KNN 32

typedef unsigned short ushort_t;
typedef ushort_t ushort8 __attribute__((ext_vector_type(8)));
typedef short short8v __attribute__((ext_vector_type(8)));
typedef float f32x4 __attribute__((ext_vector_type(4)));

static __device__ __forceinline__ float b2f(ushort_t u) {
    union { float f; unsigned int i; } v; v.i = ((unsigned int)u) << 16; return v.f;
}
static __device__ __forceinline__ ushort_t f2b(float f) {
    __hip_bfloat16 h = __float2bfloat16(f);
    return *(ushort_t*)&h;
}

// ---------------------------------------------------------------------------
// bf16 MFMA GEMM, 128x128 tile (for s-projection: M=8192, K=384, P=1152).
// ---------------------------------------------------------------------------
__global__ __launch_bounds__(256) void gemm_bf16(
    const float* __restrict__ A, const float* __restrict__ W,
    const float* __restrict__ bias, float* __restrict__ C,
    int M, int K, int P)
{
    __shared__ ushort_t As[128][40];   // [m][k]
    __shared__ ushort_t Bs[128][40];   // [n][k]

    const int tid  = threadIdx.x;
    const int row0 = blockIdx.x * 128;
    const int col0 = blockIdx.y * 128;

    const int wave = tid >> 6;
    const int lane = tid & 63;
    const int wm = (wave >> 1) * 64;
    const int wn = (wave & 1) * 64;
    const int m16 = lane & 15;
    const int kof = (lane >> 4) * 8;

    const int a_row = tid >> 1;
    const int a_kq  = (tid & 1) * 16;
    const int b_n  = tid >> 1;
    const int b_kq = (tid & 1) * 16;

    f32x4 acc[4][4];
#pragma unroll
    for (int i = 0; i < 4; ++i)
#pragma unroll
        for (int j = 0; j < 4; ++j) acc[i][j] = (f32x4)0.0f;

    for (int k0 = 0; k0 < K; k0 += 32) {
        {
            const float* ap = A + (size_t)(row0 + a_row) * K + (k0 + a_kq);
            float4 v0 = *(const float4*)(ap);
            float4 v1 = *(const float4*)(ap + 4);
            float4 v2 = *(const float4*)(ap + 8);
            float4 v3 = *(const float4*)(ap + 12);
            ushort8 u0, u1;
            u0[0] = f2b(v0.x); u0[1] = f2b(v0.y); u0[2] = f2b(v0.z); u0[3] = f2b(v0.w);
            u0[4] = f2b(v1.x); u0[5] = f2b(v1.y); u0[6] = f2b(v1.z); u0[7] = f2b(v1.w);
            u1[0] = f2b(v2.x); u1[1] = f2b(v2.y); u1[2] = f2b(v2.z); u1[3] = f2b(v2.w);
            u1[4] = f2b(v3.x); u1[5] = f2b(v3.y); u1[6] = f2b(v3.z); u1[7] = f2b(v3.w);
            *(ushort8*)&As[a_row][a_kq]     = u0;
            *(ushort8*)&As[a_row][a_kq + 8] = u1;
        }
        {
            const int col = col0 + b_n;
            ushort8 u0, u1;
            if (col < P) {
                const float* wp = W + (size_t)(k0 + b_kq) * P + col;
#pragma unroll
                for (int i = 0; i < 8; ++i) { u0[i] = f2b(*wp); wp += P; }
#pragma unroll
                for (int i = 0; i < 8; ++i) { u1[i] = f2b(*wp); wp += P; }
            } else {
                u0 = (ushort8)0; u1 = (ushort8)0;
            }
            *(ushort8*)&Bs[b_n][b_kq]     = u0;
            *(ushort8*)&Bs[b_n][b_kq + 8] = u1;
        }
        __syncthreads();

        short8v a[4], b[4];
#pragma unroll
        for (int mb = 0; mb < 4; ++mb)
            a[mb] = *(const short8v*)&As[wm + mb * 16 + m16][kof];
#pragma unroll
        for (int nb = 0; nb < 4; ++nb)
            b[nb] = *(const short8v*)&Bs[wn + nb * 16 + m16][kof];
#pragma unroll
        for (int mb = 0; mb < 4; ++mb)
#pragma unroll
            for (int nb = 0; nb < 4; ++nb)
                acc[mb][nb] = __builtin_amdgcn_mfma_f32_16x16x32_bf16(
                    a[mb], b[nb], acc[mb][nb], 0, 0, 0);
        __syncthreads();
    }

    const int r_base = row0 + wm + (lane >> 4) * 4;
#pragma unroll
    for (int nb = 0; nb < 4; ++nb) {
        const int col = col0 + wn + nb * 16 + m16;
        if (col >= P) continue;
        const float bv = bias[col];
#pragma unroll
        for (int mb = 0; mb < 4; ++mb) {
#pragma unroll
            for (int r = 0; r < 4; ++r) {
                C[(size_t)(r_base + mb * 16 + r) * P + col] = acc[mb][nb][r] + bv;
            }
        }
    }
}

// ---------------------------------------------------------------------------
// bf16 MFMA GEMM, 64x64 tile — for parallelism-starved / narrow-P GEMMs
// (out-GEMM: 768 blocks; z-GEMM: P=44 waste 31% instead of 65%).
// ---------------------------------------------------------------------------
__global__ __launch_bounds__(256) void gemm_bf16_64(
    const float* __restrict__ A, const float* __restrict__ W,
    const float* __restrict__ bias, float* __restrict__ C,
    int M, int K, int P)
{
    __shared__ ushort_t As[64][40];
    __shared__ ushort_t Bs[64][40];

    const int tid  = threadIdx.x;
    const int row0 = blockIdx.x * 64;
    const int col0 = blockIdx.y * 64;

    const int wave = tid >> 6;
    const int lane = tid & 63;
    const int wm = (wave >> 1) * 32;
    const int wn = (wave & 1) * 32;
    const int m16 = lane & 15;
    const int kof = (lane >> 4) * 8;

    const int a_row = tid >> 2;        // 0..63
    const int a_kq  = (tid & 3) * 8;   // 0,8,16,24

    f32x4 acc[2][2];
#pragma unroll
    for (int i = 0; i < 2; ++i)
#pragma unroll
        for (int j = 0; j < 2; ++j) acc[i][j] = (f32x4)0.0f;

    for (int k0 = 0; k0 < K; k0 += 32) {
        {
            const float* ap = A + (size_t)(row0 + a_row) * K + (k0 + a_kq);
            float4 v0 = *(const float4*)(ap);
            float4 v1 = *(const float4*)(ap + 4);
            ushort8 u;
            u[0] = f2b(v0.x); u[1] = f2b(v0.y); u[2] = f2b(v0.z); u[3] = f2b(v0.w);
            u[4] = f2b(v1.x); u[5] = f2b(v1.y); u[6] = f2b(v1.z); u[7] = f2b(v1.w);
            *(ushort8*)&As[a_row][a_kq] = u;
        }
        {
            const int col = col0 + a_row;
            ushort8 u;
            if (col < P) {
                const float* wp = W + (size_t)(k0 + a_kq) * P + col;
#pragma unroll
                for (int i = 0; i < 8; ++i) { u[i] = f2b(*wp); wp += P; }
            } else {
                u = (ushort8)0;
            }
            *(ushort8*)&Bs[a_row][a_kq] = u;
        }
        __syncthreads();

        short8v a[2], b[2];
#pragma unroll
        for (int mb = 0; mb < 2; ++mb)
            a[mb] = *(const short8v*)&As[wm + mb * 16 + m16][kof];
#pragma unroll
        for (int nb = 0; nb < 2; ++nb)
            b[nb] = *(const short8v*)&Bs[wn + nb * 16 + m16][kof];
#pragma unroll
        for (int mb = 0; mb < 2; ++mb)
#pragma unroll
            for (int nb = 0; nb < 2; ++nb)
                acc[mb][nb] = __builtin_amdgcn_mfma_f32_16x16x32_bf16(
                    a[mb], b[nb], acc[mb][nb], 0, 0, 0);
        __syncthreads();
    }

    const int r_base = row0 + wm + (lane >> 4) * 4;
#pragma unroll
    for (int nb = 0; nb < 2; ++nb) {
        const int col = col0 + wn + nb * 16 + m16;
        if (col >= P) continue;
        const float bv = bias[col];
#pragma unroll
        for (int mb = 0; mb < 2; ++mb) {
#pragma unroll
            for (int r = 0; r < 4; ++r) {
                C[(size_t)(r_base + mb * 16 + r) * P + col] = acc[mb][nb][r] + bv;
            }
        }
    }
}

// Build Wall (384 x 1152) = [w_q | w_kv | w_qp | w_kvp], ball(1152)
__global__ void build_wall(const float* __restrict__ wq,  const float* __restrict__ bq,
                           const float* __restrict__ wkv, const float* __restrict__ bkv,
                           const float* __restrict__ wqp, const float* __restrict__ bqp,
                           const float* __restrict__ wkvp,const float* __restrict__ bkvp,
                           float* __restrict__ Wall, float* __restrict__ ball)
{
    int t = blockIdx.x * 256 + threadIdx.x;
    if (t < 384 * 1152) {
        int c = t / 1152, j = t % 1152;
        float v;
        if      (j < 192)  v = wq  [c * 192 + j];
        else if (j < 576)  v = wkv [c * 384 + (j - 192)];
        else if (j < 720)  v = wqp [c * 144 + (j - 576)];
        else               v = wkvp[c * 432 + (j - 720)];
        Wall[t] = v;
    }
    if (t < 1152) {
        float v;
        if      (t < 192)  v = bq[t];
        else if (t < 576)  v = bkv[t - 192];
        else if (t < 720)  v = bqp[t - 576];
        else               v = bkvp[t - 720];
        ball[t] = v;
    }
}

// Concatenate w_b (128x12) | w_dz (128x32) -> Wcat (128x44)
__global__ void build_wcat(const float* __restrict__ wb, const float* __restrict__ bb,
                           const float* __restrict__ wdz, const float* __restrict__ bdz,
                           float* __restrict__ Wcat, float* __restrict__ bcat)
{
    int t = blockIdx.x * 256 + threadIdx.x;
    if (t < 128 * 44) {
        int c = t / 44, j = t % 44;
        Wcat[t] = (j < 12) ? wb[c * 12 + j] : wdz[c * 32 + (j - 12)];
    }
    if (t < 44) bcat[t] = (t < 12) ? bb[t] : bdz[t - 12];
}

// ---------------------------------------------------------------------------
// prep_tables: per node, 576 tasks (see round-1 comments)
// ---------------------------------------------------------------------------
__global__ void prep_tables(const float* __restrict__ proj_all,
                            const float* __restrict__ rot,
                            const float* __restrict__ trans,
                            float* __restrict__ q_pts,
                            float* __restrict__ kpt,
                            ushort_t* __restrict__ vpt,
                            ushort_t* __restrict__ kbt,
                            ushort_t* __restrict__ vbt)
{
    int t = blockIdx.x * 256 + threadIdx.x;
    if (t >= N_NODES * 576) return;
    const int n = t / 576;
    const int m = t % 576;
    const float* row = proj_all + (size_t)n * 1152;

    if (m >= 192) {
        const int c0 = m - 192;
        const int h = c0 >> 5, c = c0 & 31;
        ushort_t v = f2b(row[192 + c0]);
        if (c < 16) kbt[(size_t)n * 192 + h * 16 + c] = v;
        else        vbt[(size_t)n * 192 + h * 16 + (c - 16)] = v;
        return;
    }

    const float* R  = rot + n * 9;
    const float* tr = trans + n * 3;
    float X, Y, Z;
    if (m < 48) {
        const float* src = row + 576;
        X = src[m]; Y = src[48 + m]; Z = src[96 + m];
        float gx = R[0] * X + R[1] * Y + R[2] * Z + tr[0];
        float gy = R[3] * X + R[4] * Y + R[5] * Z + tr[1];
        float gz = R[6] * X + R[7] * Y + R[8] * Z + tr[2];
        const int h = m >> 2, p = m & 3;
        float* dst = q_pts + (size_t)n * 144 + h * 12 + p * 3;
        dst[0] = gx; dst[1] = gy; dst[2] = gz;
    } else {
        const int pt = m - 48;
        const int h = pt / 12, p = pt % 12;
        const float* src = row + 720;
        X = src[pt]; Y = src[144 + pt]; Z = src[288 + pt];
        float gx = R[0] * X + R[1] * Y + R[2] * Z + tr[0];
        float gy = R[3] * X + R[4] * Y + R[5] * Z + tr[1];
        float gz = R[6] * X + R[7] * Y + R[8] * Z + tr[2];
        if (p < 4) {
            float* dst = kpt + (size_t)n * 144 + h * 12 + p * 3;
            dst[0] = gx; dst[1] = gy; dst[2] = gz;
        } else {
            ushort_t* dst = vpt + (size_t)n * 288 + h * 24 + (p - 4) * 3;
            dst[0] = f2b(gx); dst[1] = f2b(gy); dst[2] = f2b(gz);
        }
    }
}

// ---------------------------------------------------------------------------
// attention: one block (256 thr) per node. zproj staged in LDS (new).
// Hand-packed 40,656B shared arena -> 4 blocks/CU (160K/40,960).
// Layout:
//   [0      .. 31744) stage: ph1 kb[32][200]u16 | kp[32][148]f32
//                            ph2 vb[32][200]u16 | vp[32][296]u16  (aliased)
//   [31744  .. 37376) zp[32][44] f32 (row 176B, 16B-aligned)
//   [37376  .. 38720) q_s[192]|qp_s[144] f32  ->  opt[12][8][3] f32 (aliased)
//   [38720  .. 40304) a_s[12][33] f32
//   [40304  .. 40656) idx[32] | madd[32] | R[9] | t[3] | hw[12]
// ---------------------------------------------------------------------------
__global__ __launch_bounds__(256) void attn_kernel(
    const float* __restrict__ q,
    const ushort_t* __restrict__ kbt,
    const ushort_t* __restrict__ vbt,
    const float* __restrict__ q_pts,
    const float* __restrict__ kpt,
    const ushort_t* __restrict__ vpt,
    const float* __restrict__ zproj,
    const int*   __restrict__ eidx,
    const float* __restrict__ mask,
    const float* __restrict__ rot,
    const float* __restrict__ trans,
    const float* __restrict__ head_weights,
    float* __restrict__ catb)
{
    const int n   = blockIdx.x;
    const int tid = threadIdx.x;

    __shared__ __align__(16) char smem[40656];
    ushort_t (*kb)[200] = (ushort_t(*)[200])smem;
    float    (*kp)[148] = (float(*)[148])(smem + 12800);
    ushort_t (*vb)[200] = (ushort_t(*)[200])smem;
    ushort_t (*vp)[296] = (ushort_t(*)[296])(smem + 12800);
    float    (*zp)[44]  = (float(*)[44])(smem + 31744);
    float*  q_s   = (float*)(smem + 37376);        // [192]
    float*  qp_s  = q_s + 192;                     // [144]
    float (*opt)[8][3] = (float(*)[8][3])(smem + 37376);  // aliases q_s/qp_s
    float (*a_s)[33]   = (float(*)[33])(smem + 38720);
    int*    idx_s  = (int*)  (smem + 40304);
    float*  madd_s = (float*)(smem + 40432);
    float*  R_s    = (float*)(smem + 40560);
    float*  t_s    = R_s + 9;
    float*  hw_s   = t_s + 3;

    // ---- seg0: node-local loads ----
    for (int i = tid; i < 192; i += 256) q_s[i]  = q[(size_t)n * 1152 + i];
    for (int i = tid; i < 144; i += 256) qp_s[i] = q_pts[(size_t)n * 144 + i];
    if (tid < 32)              idx_s[tid]     = eidx[n * 32 + tid];
    if (tid >= 32 && tid < 41) R_s[tid - 32]  = rot[n * 9 + (tid - 32)];
    if (tid >= 41 && tid < 44) t_s[tid - 41]  = trans[n * 3 + (tid - 41)];
    if (tid >= 44 && tid < 56) {
        float x = head_weights[tid - 44];
        hw_s[tid - 44] = log1pf(__expf(x)) * 0.13608276348795434f;
    }
    __syncthreads();

    // ---- seg1: mask + phase-1 staging (k bf16, k_pts f32, zproj f32) ----
    if (tid < 32) madd_s[tid] = 100000.0f * (mask[idx_s[tid]] - 1.0f);
    for (int c = tid; c < 768; c += 256) {
        const int r = c / 24, qc = c % 24;
        *(ushort8*)&kb[r][qc * 8] =
            *(const ushort8*)(kbt + (size_t)idx_s[r] * 192 + qc * 8);
    }
    for (int c = tid; c < 1152; c += 256) {
        const int r = c / 36, qc = c % 36;
        *(float4*)&kp[r][qc * 4] =
            *(const float4*)(kpt + (size_t)idx_s[r] * 144 + qc * 4);
    }
    for (int c = tid; c < 352; c += 256) {          // zproj: contiguous per node
        const int r = c / 11, qc = c % 11;
        *(float4*)&zp[r][qc * 4] =
            *(const float4*)(zproj + ((size_t)n * 32 + r) * 44 + qc * 4);
    }
    __syncthreads();

    // ---- logits: 384 (h,j) tasks ----
    for (int t = tid; t < 384; t += 256) {
        const int h = t >> 5, j = t & 31;
        ushort8 k0 = *(const ushort8*)&kb[j][h * 16];
        ushort8 k1 = *(const ushort8*)&kb[j][h * 16 + 8];
        const float* qh = q_s + h * 16;
        float dot = 0.0f;
#pragma unroll
        for (int c = 0; c < 8; ++c) dot += qh[c] * b2f(k0[c]);
#pragma unroll
        for (int c = 0; c < 8; ++c) dot += qh[8 + c] * b2f(k1[c]);

        const float* kpr = &kp[j][h * 12];
        const float* qp  = qp_s + h * 12;
        float pt = 0.0f;
#pragma unroll
        for (int e = 0; e < 12; ++e) { float d = qp[e] - kpr[e]; pt += d * d; }

        float logit = 0.14433756729740643f * dot
                    + 0.5773502691896258f * zp[j][h]
                    - 0.5f * hw_s[h] * pt
                    + madd_s[j];
        a_s[h][j] = logit;
    }
    __syncthreads();

    // ---- softmax (tid<12) overlapped with phase-2 staging ----
    if (tid < 12) {
        float m = -1e30f;
#pragma unroll
        for (int j = 0; j < 32; ++j) m = fmaxf(m, a_s[tid][j]);
        float ssum = 0.0f;
#pragma unroll
        for (int j = 0; j < 32; ++j) {
            float e = __expf(a_s[tid][j] - m);
            a_s[tid][j] = e; ssum += e;
        }
        float inv = 1.0f / ssum;
#pragma unroll
        for (int j = 0; j < 32; ++j) a_s[tid][j] *= inv;
    }
    for (int c = tid; c < 768; c += 256) {
        const int r = c / 24, qc = c % 24;
        *(ushort8*)&vb[r][qc * 8] =
            *(const ushort8*)(vbt + (size_t)idx_s[r] * 192 + qc * 8);
    }
    for (int c = tid; c < 1152; c += 256) {
        const int r = c / 36, qc = c % 36;
        *(ushort8*)&vp[r][qc * 8] =
            *(const ushort8*)(vpt + (size_t)idx_s[r] * 288 + qc * 8);
    }
    __syncthreads();

    // ---- weighted sums: o(192) | o_pt(288) | o_pair(384) ----
    float* catn = catb + (size_t)n * 960;
    for (int t = tid; t < 864; t += 256) {
        if (t < 192) {
            const int h = t >> 4, c = t & 15;
            float sacc = 0.0f;
#pragma unroll
            for (int j = 0; j < 32; ++j)
                sacc += a_s[h][j] * b2f(vb[j][h * 16 + c]);
            catn[h * 16 + c] = sacc;
        } else if (t < 480) {
            const int u = t - 192;
            const int h = u / 24, r = u % 24, p = r / 3, x = r % 3;
            float sacc = 0.0f;
#pragma unroll
            for (int j = 0; j < 32; ++j)
                sacc += a_s[h][j] * b2f(vp[j][h * 24 + p * 3 + x]);
            opt[h][p][x] = sacc;
        } else {
            const int u = t - 480;
            const int h = u >> 5, c = u & 31;
            float sacc = 0.0f;
#pragma unroll
            for (int j = 0; j < 32; ++j)
                sacc += a_s[h][j] * zp[j][12 + c];
            catn[576 + h * 32 + c] = sacc;
        }
    }
    __syncthreads();

    // ---- rotate back + norms ----
    if (tid < 96) {
        const int h = tid >> 3, p = tid & 7;
        float gx = opt[h][p][0] - t_s[0];
        float gy = opt[h][p][1] - t_s[1];
        float gz = opt[h][p][2] - t_s[2];
        float lx = R_s[0] * gx + R_s[3] * gy + R_s[6] * gz;
        float ly = R_s[1] * gx + R_s[4] * gy + R_s[7] * gz;
        float lz = R_s[2] * gx + R_s[5] * gy + R_s[8] * gz;
        const int hp = h * 8 + p;
        catn[192 + hp] = lx;
        catn[288 + hp] = ly;
        catn[384 + hp] = lz;
        catn[480 + hp] = sqrtf(lx * lx + ly * ly + lz * lz + 1e-8f);
    }
}

// ---------------------------------------------------------------------------
extern "C" void kernel_launch(void* const* d_in, const int* in_sizes, int n_in,
                              void* d_out, int out_size, void* d_ws, size_t ws_size,
                              hipStream_t stream)
{
    const float* s     = (const float*)d_in[0];
    const float* z     = (const float*)d_in[1];
    const int*   eidx  = (const int*)  d_in[2];
    const float* rot   = (const float*)d_in[3];
    const float* trans = (const float*)d_in[4];
    const float* mask  = (const float*)d_in[5];
    const float* w_q   = (const float*)d_in[6];
    const float* b_q   = (const float*)d_in[7];
    const float* w_kv  = (const float*)d_in[8];
    const float* b_kv  = (const float*)d_in[9];
    const float* w_qp  = (const float*)d_in[10];
    const float* b_qp  = (const float*)d_in[11];
    const float* w_kvp = (const float*)d_in[12];
    const float* b_kvp = (const float*)d_in[13];
    const float* w_b   = (const float*)d_in[14];
    const float* b_b   = (const float*)d_in[15];
    const float* w_dz  = (const float*)d_in[16];
    const float* b_dz  = (const float*)d_in[17];
    const float* hw    = (const float*)d_in[18];
    const float* w_out = (const float*)d_in[19];
    const float* b_out = (const float*)d_in[20];
    float* out = (float*)d_out;

    float* ws = (float*)d_ws;
    size_t off = 0;
    float* proj_all = ws + off; off += (size_t)N_NODES * 1152;
    float* q_pts    = ws + off; off += (size_t)N_NODES * 144;
    float* kpt      = ws + off; off += (size_t)N_NODES * 144;
    ushort_t* vpt   = (ushort_t*)(ws + off); off += (size_t)N_NODES * 144;
    ushort_t* kbt   = (ushort_t*)(ws + off); off += (size_t)N_NODES * 96;
    ushort_t* vbt   = (ushort_t*)(ws + off); off += (size_t)N_NODES * 96;
    float* zproj    = ws + off; off += (size_t)N_NODES * KNN * 44;
    float* catb     = ws + off; off += (size_t)N_NODES * 960;
    float* Wall     = ws + off; off += (size_t)384 * 1152;
    float* ball     = ws + off; off += 1152;
    float* Wcat     = ws + off; off += 128 * 44;
    float* bcat     = ws + off; off += 44;

    // 1) fused s-projection (q|kv|qp|kvp) via MFMA (128x128 tiles)
    build_wall<<<(384 * 1152 + 255) / 256, 256, 0, stream>>>(
        w_q, b_q, w_kv, b_kv, w_qp, b_qp, w_kvp, b_kvp, Wall, ball);
    gemm_bf16<<<dim3(N_NODES / 128, 9), 256, 0, stream>>>(s, Wall, ball, proj_all,
                                                          N_NODES, 384, 1152);

    // 2) pair projection via MFMA (64x64 tiles, P=44 masked)
    build_wcat<<<23, 256, 0, stream>>>(w_b, b_b, w_dz, b_dz, Wcat, bcat);
    gemm_bf16_64<<<dim3((N_NODES * KNN) / 64, 1), 256, 0, stream>>>(z, Wcat, bcat, zproj,
                                                                    N_NODES * KNN, 128, 44);

    // 3) gather tables: point transforms + bf16 conversions
    prep_tables<<<(N_NODES * 576 + 255) / 256, 256, 0, stream>>>(
        proj_all, rot, trans, q_pts, kpt, vpt, kbt, vbt);

    // 4) attention
    attn_kernel<<<N_NODES, 256, 0, stream>>>(
        proj_all, kbt, vbt, q_pts, kpt, vpt, zproj, eidx, mask, rot, trans, hw, catb);

    // 5) output projection via MFMA (64x64 tiles: 768 blocks)
    gemm_bf16_64<<<dim3(N_NODES / 64, 6), 256, 0, stream>>>(catb, w_out, b_out, out,
                                                            N_NODES, 960, 384);
}

// Round 5
// 230.785 us; speedup vs baseline: 2.5573x; 1.1665x over previous
//
#include <hip/hip_runtime.h>
#include <hip/hip_bf16.h>
#include <math.h>

#define N_NODES 8192
#define KNN 32

typedef unsigned short ushort_t;
typedef ushort_t ushort8 __attribute__((ext_vector_type(8)));
typedef ushort_t ushort4v __attribute__((ext_vector_type(4)));
typedef short short8v __attribute__((ext_vector_type(8)));
typedef float f32x4 __attribute__((ext_vector_type(4)));

static __device__ __forceinline__ float b2f(ushort_t u) {
    union { float f; unsigned int i; } v; v.i = ((unsigned int)u) << 16; return v.f;
}
static __device__ __forceinline__ ushort_t f2b(float f) {
    __hip_bfloat16 h = __float2bfloat16(f);
    return *(ushort_t*)&h;
}

// ---------------------------------------------------------------------------
// bf16 MFMA GEMM, 128x128 tile (s-projection: M=8192, K=384, P=1152).
// ---------------------------------------------------------------------------
__global__ __launch_bounds__(256) void gemm_bf16(
    const float* __restrict__ A, const float* __restrict__ W,
    const float* __restrict__ bias, float* __restrict__ C,
    int M, int K, int P)
{
    __shared__ ushort_t As[128][40];   // [m][k]
    __shared__ ushort_t Bs[128][40];   // [n][k]

    const int tid  = threadIdx.x;
    const int row0 = blockIdx.x * 128;
    const int col0 = blockIdx.y * 128;

    const int wave = tid >> 6;
    const int lane = tid & 63;
    const int wm = (wave >> 1) * 64;
    const int wn = (wave & 1) * 64;
    const int m16 = lane & 15;
    const int kof = (lane >> 4) * 8;

    const int a_row = tid >> 1;
    const int a_kq  = (tid & 1) * 16;
    const int b_n  = tid >> 1;
    const int b_kq = (tid & 1) * 16;

    f32x4 acc[4][4];
#pragma unroll
    for (int i = 0; i < 4; ++i)
#pragma unroll
        for (int j = 0; j < 4; ++j) acc[i][j] = (f32x4)0.0f;

    for (int k0 = 0; k0 < K; k0 += 32) {
        {
            const float* ap = A + (size_t)(row0 + a_row) * K + (k0 + a_kq);
            float4 v0 = *(const float4*)(ap);
            float4 v1 = *(const float4*)(ap + 4);
            float4 v2 = *(const float4*)(ap + 8);
            float4 v3 = *(const float4*)(ap + 12);
            ushort8 u0, u1;
            u0[0] = f2b(v0.x); u0[1] = f2b(v0.y); u0[2] = f2b(v0.z); u0[3] = f2b(v0.w);
            u0[4] = f2b(v1.x); u0[5] = f2b(v1.y); u0[6] = f2b(v1.z); u0[7] = f2b(v1.w);
            u1[0] = f2b(v2.x); u1[1] = f2b(v2.y); u1[2] = f2b(v2.z); u1[3] = f2b(v2.w);
            u1[4] = f2b(v3.x); u1[5] = f2b(v3.y); u1[6] = f2b(v3.z); u1[7] = f2b(v3.w);
            *(ushort8*)&As[a_row][a_kq]     = u0;
            *(ushort8*)&As[a_row][a_kq + 8] = u1;
        }
        {
            const int col = col0 + b_n;
            ushort8 u0, u1;
            if (col < P) {
                const float* wp = W + (size_t)(k0 + b_kq) * P + col;
#pragma unroll
                for (int i = 0; i < 8; ++i) { u0[i] = f2b(*wp); wp += P; }
#pragma unroll
                for (int i = 0; i < 8; ++i) { u1[i] = f2b(*wp); wp += P; }
            } else {
                u0 = (ushort8)0; u1 = (ushort8)0;
            }
            *(ushort8*)&Bs[b_n][b_kq]     = u0;
            *(ushort8*)&Bs[b_n][b_kq + 8] = u1;
        }
        __syncthreads();

        short8v a[4], b[4];
#pragma unroll
        for (int mb = 0; mb < 4; ++mb)
            a[mb] = *(const short8v*)&As[wm + mb * 16 + m16][kof];
#pragma unroll
        for (int nb = 0; nb < 4; ++nb)
            b[nb] = *(const short8v*)&Bs[wn + nb * 16 + m16][kof];
#pragma unroll
        for (int mb = 0; mb < 4; ++mb)
#pragma unroll
            for (int nb = 0; nb < 4; ++nb)
                acc[mb][nb] = __builtin_amdgcn_mfma_f32_16x16x32_bf16(
                    a[mb], b[nb], acc[mb][nb], 0, 0, 0);
        __syncthreads();
    }

    const int r_base = row0 + wm + (lane >> 4) * 4;
#pragma unroll
    for (int nb = 0; nb < 4; ++nb) {
        const int col = col0 + wn + nb * 16 + m16;
        if (col >= P) continue;
        const float bv = bias[col];
#pragma unroll
        for (int mb = 0; mb < 4; ++mb) {
#pragma unroll
            for (int r = 0; r < 4; ++r) {
                C[(size_t)(r_base + mb * 16 + r) * P + col] = acc[mb][nb][r] + bv;
            }
        }
    }
}

// ---------------------------------------------------------------------------
// bf16 MFMA GEMM, 64x64 tile — parallelism-starved / narrow-P GEMMs.
// ---------------------------------------------------------------------------
__global__ __launch_bounds__(256) void gemm_bf16_64(
    const float* __restrict__ A, const float* __restrict__ W,
    const float* __restrict__ bias, float* __restrict__ C,
    int M, int K, int P)
{
    __shared__ ushort_t As[64][40];
    __shared__ ushort_t Bs[64][40];

    const int tid  = threadIdx.x;
    const int row0 = blockIdx.x * 64;
    const int col0 = blockIdx.y * 64;

    const int wave = tid >> 6;
    const int lane = tid & 63;
    const int wm = (wave >> 1) * 32;
    const int wn = (wave & 1) * 32;
    const int m16 = lane & 15;
    const int kof = (lane >> 4) * 8;

    const int a_row = tid >> 2;
    const int a_kq  = (tid & 3) * 8;

    f32x4 acc[2][2];
#pragma unroll
    for (int i = 0; i < 2; ++i)
#pragma unroll
        for (int j = 0; j < 2; ++j) acc[i][j] = (f32x4)0.0f;

    for (int k0 = 0; k0 < K; k0 += 32) {
        {
            const float* ap = A + (size_t)(row0 + a_row) * K + (k0 + a_kq);
            float4 v0 = *(const float4*)(ap);
            float4 v1 = *(const float4*)(ap + 4);
            ushort8 u;
            u[0] = f2b(v0.x); u[1] = f2b(v0.y); u[2] = f2b(v0.z); u[3] = f2b(v0.w);
            u[4] = f2b(v1.x); u[5] = f2b(v1.y); u[6] = f2b(v1.z); u[7] = f2b(v1.w);
            *(ushort8*)&As[a_row][a_kq] = u;
        }
        {
            const int col = col0 + a_row;
            ushort8 u;
            if (col < P) {
                const float* wp = W + (size_t)(k0 + a_kq) * P + col;
#pragma unroll
                for (int i = 0; i < 8; ++i) { u[i] = f2b(*wp); wp += P; }
            } else {
                u = (ushort8)0;
            }
            *(ushort8*)&Bs[a_row][a_kq] = u;
        }
        __syncthreads();

        short8v a[2], b[2];
#pragma unroll
        for (int mb = 0; mb < 2; ++mb)
            a[mb] = *(const short8v*)&As[wm + mb * 16 + m16][kof];
#pragma unroll
        for (int nb = 0; nb < 2; ++nb)
            b[nb] = *(const short8v*)&Bs[wn + nb * 16 + m16][kof];
#pragma unroll
        for (int mb = 0; mb < 2; ++mb)
#pragma unroll
            for (int nb = 0; nb < 2; ++nb)
                acc[mb][nb] = __builtin_amdgcn_mfma_f32_16x16x32_bf16(
                    a[mb], b[nb], acc[mb][nb], 0, 0, 0);
        __syncthreads();
    }

    const int r_base = row0 + wm + (lane >> 4) * 4;
#pragma unroll
    for (int nb = 0; nb < 2; ++nb) {
        const int col = col0 + wn + nb * 16 + m16;
        if (col >= P) continue;
        const float bv = bias[col];
#pragma unroll
        for (int mb = 0; mb < 2; ++mb) {
#pragma unroll
            for (int r = 0; r < 4; ++r) {
                C[(size_t)(r_base + mb * 16 + r) * P + col] = acc[mb][nb][r] + bv;
            }
        }
    }
}

// Build Wall (384 x 1152) = [w_q | w_kv | w_qp | w_kvp], ball(1152)
__global__ void build_wall(const float* __restrict__ wq,  const float* __restrict__ bq,
                           const float* __restrict__ wkv, const float* __restrict__ bkv,
                           const float* __restrict__ wqp, const float* __restrict__ bqp,
                           const float* __restrict__ wkvp,const float* __restrict__ bkvp,
                           float* __restrict__ Wall, float* __restrict__ ball)
{
    int t = blockIdx.x * 256 + threadIdx.x;
    if (t < 384 * 1152) {
        int c = t / 1152, j = t % 1152;
        float v;
        if      (j < 192)  v = wq  [c * 192 + j];
        else if (j < 576)  v = wkv [c * 384 + (j - 192)];
        else if (j < 720)  v = wqp [c * 144 + (j - 576)];
        else               v = wkvp[c * 432 + (j - 720)];
        Wall[t] = v;
    }
    if (t < 1152) {
        float v;
        if      (t < 192)  v = bq[t];
        else if (t < 576)  v = bkv[t - 192];
        else if (t < 720)  v = bqp[t - 576];
        else               v = bkvp[t - 720];
        ball[t] = v;
    }
}

// Concatenate w_b (128x12) | w_dz (128x32) -> Wcat (128x44)
__global__ void build_wcat(const float* __restrict__ wb, const float* __restrict__ bb,
                           const float* __restrict__ wdz, const float* __restrict__ bdz,
                           float* __restrict__ Wcat, float* __restrict__ bcat)
{
    int t = blockIdx.x * 256 + threadIdx.x;
    if (t < 128 * 44) {
        int c = t / 44, j = t % 44;
        Wcat[t] = (j < 12) ? wb[c * 12 + j] : wdz[c * 32 + (j - 12)];
    }
    if (t < 44) bcat[t] = (t < 12) ? bb[t] : bdz[t - 12];
}

// ---------------------------------------------------------------------------
// prep_tables: per node, 576 tasks (unchanged)
// ---------------------------------------------------------------------------
__global__ void prep_tables(const float* __restrict__ proj_all,
                            const float* __restrict__ rot,
                            const float* __restrict__ trans,
                            float* __restrict__ q_pts,
                            float* __restrict__ kpt,
                            ushort_t* __restrict__ vpt,
                            ushort_t* __restrict__ kbt,
                            ushort_t* __restrict__ vbt)
{
    int t = blockIdx.x * 256 + threadIdx.x;
    if (t >= N_NODES * 576) return;
    const int n = t / 576;
    const int m = t % 576;
    const float* row = proj_all + (size_t)n * 1152;

    if (m >= 192) {
        const int c0 = m - 192;
        const int h = c0 >> 5, c = c0 & 31;
        ushort_t v = f2b(row[192 + c0]);
        if (c < 16) kbt[(size_t)n * 192 + h * 16 + c] = v;
        else        vbt[(size_t)n * 192 + h * 16 + (c - 16)] = v;
        return;
    }

    const float* R  = rot + n * 9;
    const float* tr = trans + n * 3;
    float X, Y, Z;
    if (m < 48) {
        const float* src = row + 576;
        X = src[m]; Y = src[48 + m]; Z = src[96 + m];
        float gx = R[0] * X + R[1] * Y + R[2] * Z + tr[0];
        float gy = R[3] * X + R[4] * Y + R[5] * Z + tr[1];
        float gz = R[6] * X + R[7] * Y + R[8] * Z + tr[2];
        const int h = m >> 2, p = m & 3;
        float* dst = q_pts + (size_t)n * 144 + h * 12 + p * 3;
        dst[0] = gx; dst[1] = gy; dst[2] = gz;
    } else {
        const int pt = m - 48;
        const int h = pt / 12, p = pt % 12;
        const float* src = row + 720;
        X = src[pt]; Y = src[144 + pt]; Z = src[288 + pt];
        float gx = R[0] * X + R[1] * Y + R[2] * Z + tr[0];
        float gy = R[3] * X + R[4] * Y + R[5] * Z + tr[1];
        float gz = R[6] * X + R[7] * Y + R[8] * Z + tr[2];
        if (p < 4) {
            float* dst = kpt + (size_t)n * 144 + h * 12 + p * 3;
            dst[0] = gx; dst[1] = gy; dst[2] = gz;
        } else {
            ushort_t* dst = vpt + (size_t)n * 288 + h * 24 + (p - 4) * 3;
            dst[0] = f2b(gx); dst[1] = f2b(gy); dst[2] = f2b(gz);
        }
    }
}

// ---------------------------------------------------------------------------
// attention, de-staged: one block (256 thr) per node.
// Zero-reuse data (k, k_pts, v, v_pts) read DIRECTLY from global:
//   - logits: per-(h,j) 16B-granule gathers (same traffic as old staging loads)
//   - weighted sums: per-j wave-coalesced b64 row reads
// LDS keeps only reused data: zp (12x), q/qp (32x), a_s, opt. ~10KB ->
// 8 blocks/CU (wave-capped); __launch_bounds__(256,8) pins VGPR<=64.
// ---------------------------------------------------------------------------
__global__ __launch_bounds__(256, 8) void attn_kernel(
    const float* __restrict__ q,           // proj_all (stride 1152, cols 0..191)
    const ushort_t* __restrict__ kbt,      // N x 192 bf16
    const ushort_t* __restrict__ vbt,      // N x 192 bf16
    const float* __restrict__ q_pts,       // N x 144 f32
    const float* __restrict__ kpt,         // N x 144 f32
    const ushort_t* __restrict__ vpt,      // N x 288 bf16
    const float* __restrict__ zproj,       // (N*K) x 44 f32
    const int*   __restrict__ eidx,
    const float* __restrict__ mask,
    const float* __restrict__ rot,
    const float* __restrict__ trans,
    const float* __restrict__ head_weights,
    float* __restrict__ catb)
{
    const int n   = blockIdx.x;
    const int tid = threadIdx.x;

    __shared__ float zp[32][44];        // 5632B (row 176B, float4-aligned)
    __shared__ float q_s[192];
    __shared__ float qp_s[144];
    __shared__ float a_s[12][33];
    __shared__ float opt[288];          // h*24 + p*3 + x
    __shared__ int   idx_s[32];
    __shared__ float R_s[9];
    __shared__ float t_s[3];
    __shared__ float hw_s[12];

    // ---- phase 0: stage reused data ----
    for (int i = tid; i < 192; i += 256) q_s[i]  = q[(size_t)n * 1152 + i];
    for (int i = tid; i < 144; i += 256) qp_s[i] = q_pts[(size_t)n * 144 + i];
    if (tid < 32)              idx_s[tid]     = eidx[n * 32 + tid];
    if (tid >= 32 && tid < 41) R_s[tid - 32]  = rot[n * 9 + (tid - 32)];
    if (tid >= 41 && tid < 44) t_s[tid - 41]  = trans[n * 3 + (tid - 41)];
    if (tid >= 44 && tid < 56) {
        float x = head_weights[tid - 44];
        hw_s[tid - 44] = log1pf(__expf(x)) * 0.13608276348795434f; // softplus*sqrt(1/54)
    }
    for (int c = tid; c < 352; c += 256) {      // zproj: contiguous per node
        const int r = c / 11, qc = c % 11;
        *(float4*)&zp[r][qc * 4] =
            *(const float4*)(zproj + ((size_t)n * 32 + r) * 44 + qc * 4);
    }
    __syncthreads();

    // ---- phase 1: logits, direct gather ----
    for (int t = tid; t < 384; t += 256) {
        const int h = t >> 5, j = t & 31;
        const int ix = idx_s[j];
        const ushort_t* kr = kbt + (size_t)ix * 192 + h * 16;
        ushort8 k0 = *(const ushort8*)(kr);
        ushort8 k1 = *(const ushort8*)(kr + 8);
        const float* kpr = kpt + (size_t)ix * 144 + h * 12;
        float4 p0 = *(const float4*)(kpr);
        float4 p1 = *(const float4*)(kpr + 4);
        float4 p2 = *(const float4*)(kpr + 8);
        const float mval = mask[ix];

        const float* qh = q_s + h * 16;
        float dot = 0.0f;
#pragma unroll
        for (int c = 0; c < 8; ++c) dot += qh[c] * b2f(k0[c]);
#pragma unroll
        for (int c = 0; c < 8; ++c) dot += qh[8 + c] * b2f(k1[c]);

        const float* qp = qp_s + h * 12;
        float d, pt = 0.0f;
        d = qp[0]  - p0.x; pt += d * d;  d = qp[1]  - p0.y; pt += d * d;
        d = qp[2]  - p0.z; pt += d * d;  d = qp[3]  - p0.w; pt += d * d;
        d = qp[4]  - p1.x; pt += d * d;  d = qp[5]  - p1.y; pt += d * d;
        d = qp[6]  - p1.z; pt += d * d;  d = qp[7]  - p1.w; pt += d * d;
        d = qp[8]  - p2.x; pt += d * d;  d = qp[9]  - p2.y; pt += d * d;
        d = qp[10] - p2.z; pt += d * d;  d = qp[11] - p2.w; pt += d * d;

        a_s[h][j] = 0.14433756729740643f * dot
                  + 0.5773502691896258f * zp[j][h]
                  - 0.5f * hw_s[h] * pt
                  + 100000.0f * (mval - 1.0f);
    }
    __syncthreads();

    // ---- phase 2: parallel softmax (96 threads, 8-lane shuffle groups) ----
    if (tid < 96) {
        const int h = tid >> 3, g = tid & 7;       // lanes h*8+g within wave
        float a0 = a_s[h][g * 4 + 0], a1 = a_s[h][g * 4 + 1];
        float a2 = a_s[h][g * 4 + 2], a3 = a_s[h][g * 4 + 3];
        float m = fmaxf(fmaxf(a0, a1), fmaxf(a2, a3));
        m = fmaxf(m, __shfl_xor(m, 1)); m = fmaxf(m, __shfl_xor(m, 2));
        m = fmaxf(m, __shfl_xor(m, 4));
        float e0 = __expf(a0 - m), e1 = __expf(a1 - m);
        float e2 = __expf(a2 - m), e3 = __expf(a3 - m);
        float s = e0 + e1 + e2 + e3;
        s += __shfl_xor(s, 1); s += __shfl_xor(s, 2); s += __shfl_xor(s, 4);
        const float inv = 1.0f / s;
        a_s[h][g * 4 + 0] = e0 * inv; a_s[h][g * 4 + 1] = e1 * inv;
        a_s[h][g * 4 + 2] = e2 * inv; a_s[h][g * 4 + 3] = e3 * inv;
    }
    __syncthreads();

    // ---- phase 3: weighted sums, wave-coalesced direct reads ----
    float* catn = catb + (size_t)n * 960;
    if (tid < 48) {                      // o: (h, c-quad)
        const int h = tid >> 2, cq = tid & 3;
        const ushort_t* base = vbt + h * 16 + cq * 4;
        float s0 = 0, s1 = 0, s2 = 0, s3 = 0;
#pragma unroll 4
        for (int j = 0; j < 32; ++j) {
            const int ix = idx_s[j];
            const float aj = a_s[h][j];
            ushort4v v = *(const ushort4v*)(base + (size_t)ix * 192);
            s0 += aj * b2f(v[0]); s1 += aj * b2f(v[1]);
            s2 += aj * b2f(v[2]); s3 += aj * b2f(v[3]);
        }
        float4 o = { s0, s1, s2, s3 };
        *(float4*)&catn[h * 16 + cq * 4] = o;
    } else if (tid < 120) {              // o_pt: (h, quad of 24)
        const int u = tid - 48;
        const int h = u / 6, rq = u % 6;
        const ushort_t* base = vpt + h * 24 + rq * 4;
        float s0 = 0, s1 = 0, s2 = 0, s3 = 0;
#pragma unroll 4
        for (int j = 0; j < 32; ++j) {
            const int ix = idx_s[j];
            const float aj = a_s[h][j];
            ushort4v v = *(const ushort4v*)(base + (size_t)ix * 288);
            s0 += aj * b2f(v[0]); s1 += aj * b2f(v[1]);
            s2 += aj * b2f(v[2]); s3 += aj * b2f(v[3]);
        }
        float* od = opt + h * 24 + rq * 4;
        od[0] = s0; od[1] = s1; od[2] = s2; od[3] = s3;
    } else if (tid < 216) {              // o_pair: (h, c-quad of 32)
        const int u = tid - 120;
        const int h = u >> 3, cq = u & 7;
        f32x4 acc = (f32x4)0.0f;
#pragma unroll 4
        for (int j = 0; j < 32; ++j) {
            const float aj = a_s[h][j];
            f32x4 zv = *(const f32x4*)&zp[j][12 + cq * 4];
            acc += aj * zv;
        }
        *(f32x4*)&catn[576 + h * 32 + cq * 4] = acc;
    }
    __syncthreads();

    // ---- phase 4: rotate back + norms ----
    if (tid < 96) {
        const int h = tid >> 3, p = tid & 7;
        const float* ob = opt + h * 24 + p * 3;
        float gx = ob[0] - t_s[0];
        float gy = ob[1] - t_s[1];
        float gz = ob[2] - t_s[2];
        float lx = R_s[0] * gx + R_s[3] * gy + R_s[6] * gz;
        float ly = R_s[1] * gx + R_s[4] * gy + R_s[7] * gz;
        float lz = R_s[2] * gx + R_s[5] * gy + R_s[8] * gz;
        const int hp = h * 8 + p;
        catn[192 + hp] = lx;
        catn[288 + hp] = ly;
        catn[384 + hp] = lz;
        catn[480 + hp] = sqrtf(lx * lx + ly * ly + lz * lz + 1e-8f);
    }
}

// ---------------------------------------------------------------------------
extern "C" void kernel_launch(void* const* d_in, const int* in_sizes, int n_in,
                              void* d_out, int out_size, void* d_ws, size_t ws_size,
                              hipStream_t stream)
{
    const float* s     = (const float*)d_in[0];
    const float* z     = (const float*)d_in[1];
    const int*   eidx  = (const int*)  d_in[2];
    const float* rot   = (const float*)d_in[3];
    const float* trans = (const float*)d_in[4];
    const float* mask  = (const float*)d_in[5];
    const float* w_q   = (const float*)d_in[6];
    const float* b_q   = (const float*)d_in[7];
    const float* w_kv  = (const float*)d_in[8];
    const float* b_kv  = (const float*)d_in[9];
    const float* w_qp  = (const float*)d_in[10];
    const float* b_qp  = (const float*)d_in[11];
    const float* w_kvp = (const float*)d_in[12];
    const float* b_kvp = (const float*)d_in[13];
    const float* w_b   = (const float*)d_in[14];
    const float* b_b   = (const float*)d_in[15];
    const float* w_dz  = (const float*)d_in[16];
    const float* b_dz  = (const float*)d_in[17];
    const float* hw    = (const float*)d_in[18];
    const float* w_out = (const float*)d_in[19];
    const float* b_out = (const float*)d_in[20];
    float* out = (float*)d_out;

    float* ws = (float*)d_ws;
    size_t off = 0;
    float* proj_all = ws + off; off += (size_t)N_NODES * 1152;
    float* q_pts    = ws + off; off += (size_t)N_NODES * 144;
    float* kpt      = ws + off; off += (size_t)N_NODES * 144;
    ushort_t* vpt   = (ushort_t*)(ws + off); off += (size_t)N_NODES * 144;
    ushort_t* kbt   = (ushort_t*)(ws + off); off += (size_t)N_NODES * 96;
    ushort_t* vbt   = (ushort_t*)(ws + off); off += (size_t)N_NODES * 96;
    float* zproj    = ws + off; off += (size_t)N_NODES * KNN * 44;
    float* catb     = ws + off; off += (size_t)N_NODES * 960;
    float* Wall     = ws + off; off += (size_t)384 * 1152;
    float* ball     = ws + off; off += 1152;
    float* Wcat     = ws + off; off += 128 * 44;
    float* bcat     = ws + off; off += 44;

    // 1) fused s-projection (q|kv|qp|kvp) via MFMA (128x128 tiles)
    build_wall<<<(384 * 1152 + 255) / 256, 256, 0, stream>>>(
        w_q, b_q, w_kv, b_kv, w_qp, b_qp, w_kvp, b_kvp, Wall, ball);
    gemm_bf16<<<dim3(N_NODES / 128, 9), 256, 0, stream>>>(s, Wall, ball, proj_all,
                                                          N_NODES, 384, 1152);

    // 2) pair projection via MFMA (64x64 tiles, P=44 masked)
    build_wcat<<<23, 256, 0, stream>>>(w_b, b_b, w_dz, b_dz, Wcat, bcat);
    gemm_bf16_64<<<dim3((N_NODES * KNN) / 64, 1), 256, 0, stream>>>(z, Wcat, bcat, zproj,
                                                                    N_NODES * KNN, 128, 44);

    // 3) gather tables: point transforms + bf16 conversions
    prep_tables<<<(N_NODES * 576 + 255) / 256, 256, 0, stream>>>(
        proj_all, rot, trans, q_pts, kpt, vpt, kbt, vbt);

    // 4) attention (de-staged)
    attn_kernel<<<N_NODES, 256, 0, stream>>>(
        proj_all, kbt, vbt, q_pts, kpt, vpt, zproj, eidx, mask, rot, trans, hw, catb);

    // 5) output projection via MFMA (64x64 tiles: 768 blocks)
    gemm_bf16_64<<<dim3(N_NODES / 64, 6), 256, 0, stream>>>(catb, w_out, b_out, out,
                                                            N_NODES, 960, 384);
}

// Round 6
// 202.569 us; speedup vs baseline: 2.9135x; 1.1393x over previous
//
#include <hip/hip_runtime.h>
#include <hip/hip_bf16.h>
#include <math.h>

#define N_NODES 8192
#define KNN 32

typedef unsigned short ushort_t;
typedef ushort_t ushort8 __attribute__((ext_vector_type(8)));
typedef ushort_t ushort4v __attribute__((ext_vector_type(4)));
typedef short short8v __attribute__((ext_vector_type(8)));
typedef float f32x4 __attribute__((ext_vector_type(4)));

static __device__ __forceinline__ float b2f(ushort_t u) {
    union { float f; unsigned int i; } v; v.i = ((unsigned int)u) << 16; return v.f;
}
static __device__ __forceinline__ ushort_t f2b(float f) {
    __hip_bfloat16 h = __float2bfloat16(f);
    return *(ushort_t*)&h;
}

// ---------------------------------------------------------------------------
// bf16 MFMA GEMM, 128x128 tile (s-projection: M=8192, K=384, P=1152).
// ---------------------------------------------------------------------------
__global__ __launch_bounds__(256) void gemm_bf16(
    const float* __restrict__ A, const float* __restrict__ W,
    const float* __restrict__ bias, float* __restrict__ C,
    int M, int K, int P)
{
    __shared__ ushort_t As[128][40];   // [m][k]
    __shared__ ushort_t Bs[128][40];   // [n][k]

    const int tid  = threadIdx.x;
    const int row0 = blockIdx.x * 128;
    const int col0 = blockIdx.y * 128;

    const int wave = tid >> 6;
    const int lane = tid & 63;
    const int wm = (wave >> 1) * 64;
    const int wn = (wave & 1) * 64;
    const int m16 = lane & 15;
    const int kof = (lane >> 4) * 8;

    const int a_row = tid >> 1;
    const int a_kq  = (tid & 1) * 16;
    const int b_n  = tid >> 1;
    const int b_kq = (tid & 1) * 16;

    f32x4 acc[4][4];
#pragma unroll
    for (int i = 0; i < 4; ++i)
#pragma unroll
        for (int j = 0; j < 4; ++j) acc[i][j] = (f32x4)0.0f;

    for (int k0 = 0; k0 < K; k0 += 32) {
        {
            const float* ap = A + (size_t)(row0 + a_row) * K + (k0 + a_kq);
            float4 v0 = *(const float4*)(ap);
            float4 v1 = *(const float4*)(ap + 4);
            float4 v2 = *(const float4*)(ap + 8);
            float4 v3 = *(const float4*)(ap + 12);
            ushort8 u0, u1;
            u0[0] = f2b(v0.x); u0[1] = f2b(v0.y); u0[2] = f2b(v0.z); u0[3] = f2b(v0.w);
            u0[4] = f2b(v1.x); u0[5] = f2b(v1.y); u0[6] = f2b(v1.z); u0[7] = f2b(v1.w);
            u1[0] = f2b(v2.x); u1[1] = f2b(v2.y); u1[2] = f2b(v2.z); u1[3] = f2b(v2.w);
            u1[4] = f2b(v3.x); u1[5] = f2b(v3.y); u1[6] = f2b(v3.z); u1[7] = f2b(v3.w);
            *(ushort8*)&As[a_row][a_kq]     = u0;
            *(ushort8*)&As[a_row][a_kq + 8] = u1;
        }
        {
            const int col = col0 + b_n;
            ushort8 u0, u1;
            if (col < P) {
                const float* wp = W + (size_t)(k0 + b_kq) * P + col;
#pragma unroll
                for (int i = 0; i < 8; ++i) { u0[i] = f2b(*wp); wp += P; }
#pragma unroll
                for (int i = 0; i < 8; ++i) { u1[i] = f2b(*wp); wp += P; }
            } else {
                u0 = (ushort8)0; u1 = (ushort8)0;
            }
            *(ushort8*)&Bs[b_n][b_kq]     = u0;
            *(ushort8*)&Bs[b_n][b_kq + 8] = u1;
        }
        __syncthreads();

        short8v a[4], b[4];
#pragma unroll
        for (int mb = 0; mb < 4; ++mb)
            a[mb] = *(const short8v*)&As[wm + mb * 16 + m16][kof];
#pragma unroll
        for (int nb = 0; nb < 4; ++nb)
            b[nb] = *(const short8v*)&Bs[wn + nb * 16 + m16][kof];
#pragma unroll
        for (int mb = 0; mb < 4; ++mb)
#pragma unroll
            for (int nb = 0; nb < 4; ++nb)
                acc[mb][nb] = __builtin_amdgcn_mfma_f32_16x16x32_bf16(
                    a[mb], b[nb], acc[mb][nb], 0, 0, 0);
        __syncthreads();
    }

    const int r_base = row0 + wm + (lane >> 4) * 4;
#pragma unroll
    for (int nb = 0; nb < 4; ++nb) {
        const int col = col0 + wn + nb * 16 + m16;
        if (col >= P) continue;
        const float bv = bias[col];
#pragma unroll
        for (int mb = 0; mb < 4; ++mb) {
#pragma unroll
            for (int r = 0; r < 4; ++r) {
                C[(size_t)(r_base + mb * 16 + r) * P + col] = acc[mb][nb][r] + bv;
            }
        }
    }
}

// ---------------------------------------------------------------------------
// bf16 MFMA GEMM, 64x64 tile — out-GEMM (more blocks, less tail).
// ---------------------------------------------------------------------------
__global__ __launch_bounds__(256) void gemm_bf16_64(
    const float* __restrict__ A, const float* __restrict__ W,
    const float* __restrict__ bias, float* __restrict__ C,
    int M, int K, int P)
{
    __shared__ ushort_t As[64][40];
    __shared__ ushort_t Bs[64][40];

    const int tid  = threadIdx.x;
    const int row0 = blockIdx.x * 64;
    const int col0 = blockIdx.y * 64;

    const int wave = tid >> 6;
    const int lane = tid & 63;
    const int wm = (wave >> 1) * 32;
    const int wn = (wave & 1) * 32;
    const int m16 = lane & 15;
    const int kof = (lane >> 4) * 8;

    const int a_row = tid >> 2;
    const int a_kq  = (tid & 3) * 8;

    f32x4 acc[2][2];
#pragma unroll
    for (int i = 0; i < 2; ++i)
#pragma unroll
        for (int j = 0; j < 2; ++j) acc[i][j] = (f32x4)0.0f;

    for (int k0 = 0; k0 < K; k0 += 32) {
        {
            const float* ap = A + (size_t)(row0 + a_row) * K + (k0 + a_kq);
            float4 v0 = *(const float4*)(ap);
            float4 v1 = *(const float4*)(ap + 4);
            ushort8 u;
            u[0] = f2b(v0.x); u[1] = f2b(v0.y); u[2] = f2b(v0.z); u[3] = f2b(v0.w);
            u[4] = f2b(v1.x); u[5] = f2b(v1.y); u[6] = f2b(v1.z); u[7] = f2b(v1.w);
            *(ushort8*)&As[a_row][a_kq] = u;
        }
        {
            const int col = col0 + a_row;
            ushort8 u;
            if (col < P) {
                const float* wp = W + (size_t)(k0 + a_kq) * P + col;
#pragma unroll
                for (int i = 0; i < 8; ++i) { u[i] = f2b(*wp); wp += P; }
            } else {
                u = (ushort8)0;
            }
            *(ushort8*)&Bs[a_row][a_kq] = u;
        }
        __syncthreads();

        short8v a[2], b[2];
#pragma unroll
        for (int mb = 0; mb < 2; ++mb)
            a[mb] = *(const short8v*)&As[wm + mb * 16 + m16][kof];
#pragma unroll
        for (int nb = 0; nb < 2; ++nb)
            b[nb] = *(const short8v*)&Bs[wn + nb * 16 + m16][kof];
#pragma unroll
        for (int mb = 0; mb < 2; ++mb)
#pragma unroll
            for (int nb = 0; nb < 2; ++nb)
                acc[mb][nb] = __builtin_amdgcn_mfma_f32_16x16x32_bf16(
                    a[mb], b[nb], acc[mb][nb], 0, 0, 0);
        __syncthreads();
    }

    const int r_base = row0 + wm + (lane >> 4) * 4;
#pragma unroll
    for (int nb = 0; nb < 2; ++nb) {
        const int col = col0 + wn + nb * 16 + m16;
        if (col >= P) continue;
        const float bv = bias[col];
#pragma unroll
        for (int mb = 0; mb < 2; ++mb) {
#pragma unroll
            for (int r = 0; r < 4; ++r) {
                C[(size_t)(r_base + mb * 16 + r) * P + col] = acc[mb][nb][r] + bv;
            }
        }
    }
}

// Build Wall (384 x 1152) = [w_q | w_kv | w_qp | w_kvp], ball(1152)
__global__ void build_wall(const float* __restrict__ wq,  const float* __restrict__ bq,
                           const float* __restrict__ wkv, const float* __restrict__ bkv,
                           const float* __restrict__ wqp, const float* __restrict__ bqp,
                           const float* __restrict__ wkvp,const float* __restrict__ bkvp,
                           float* __restrict__ Wall, float* __restrict__ ball)
{
    int t = blockIdx.x * 256 + threadIdx.x;
    if (t < 384 * 1152) {
        int c = t / 1152, j = t % 1152;
        float v;
        if      (j < 192)  v = wq  [c * 192 + j];
        else if (j < 576)  v = wkv [c * 384 + (j - 192)];
        else if (j < 720)  v = wqp [c * 144 + (j - 576)];
        else               v = wkvp[c * 432 + (j - 720)];
        Wall[t] = v;
    }
    if (t < 1152) {
        float v;
        if      (t < 192)  v = bq[t];
        else if (t < 576)  v = bkv[t - 192];
        else if (t < 720)  v = bqp[t - 576];
        else               v = bkvp[t - 720];
        ball[t] = v;
    }
}

// Build transposed bf16 pair-weights: WcatT[48][128] (rows 44..47 zero), bcat[44]
__global__ void build_wcatT(const float* __restrict__ wb, const float* __restrict__ bb,
                            const float* __restrict__ wdz, const float* __restrict__ bdz,
                            ushort_t* __restrict__ WcatT, float* __restrict__ bcat)
{
    int t = blockIdx.x * 256 + threadIdx.x;
    if (t < 48 * 128) {
        int j = t >> 7, c = t & 127;
        float v = (j < 12) ? wb[c * 12 + j] : (j < 44 ? wdz[c * 32 + (j - 12)] : 0.0f);
        WcatT[t] = f2b(v);
    }
    if (t < 44) bcat[t] = (t < 12) ? bb[t] : bdz[t - 12];
}

// ---------------------------------------------------------------------------
// prep_tables: per node, 576 tasks (unchanged)
// ---------------------------------------------------------------------------
__global__ void prep_tables(const float* __restrict__ proj_all,
                            const float* __restrict__ rot,
                            const float* __restrict__ trans,
                            float* __restrict__ q_pts,
                            float* __restrict__ kpt,
                            ushort_t* __restrict__ vpt,
                            ushort_t* __restrict__ kbt,
                            ushort_t* __restrict__ vbt)
{
    int t = blockIdx.x * 256 + threadIdx.x;
    if (t >= N_NODES * 576) return;
    const int n = t / 576;
    const int m = t % 576;
    const float* row = proj_all + (size_t)n * 1152;

    if (m >= 192) {
        const int c0 = m - 192;
        const int h = c0 >> 5, c = c0 & 31;
        ushort_t v = f2b(row[192 + c0]);
        if (c < 16) kbt[(size_t)n * 192 + h * 16 + c] = v;
        else        vbt[(size_t)n * 192 + h * 16 + (c - 16)] = v;
        return;
    }

    const float* R  = rot + n * 9;
    const float* tr = trans + n * 3;
    float X, Y, Z;
    if (m < 48) {
        const float* src = row + 576;
        X = src[m]; Y = src[48 + m]; Z = src[96 + m];
        float gx = R[0] * X + R[1] * Y + R[2] * Z + tr[0];
        float gy = R[3] * X + R[4] * Y + R[5] * Z + tr[1];
        float gz = R[6] * X + R[7] * Y + R[8] * Z + tr[2];
        const int h = m >> 2, p = m & 3;
        float* dst = q_pts + (size_t)n * 144 + h * 12 + p * 3;
        dst[0] = gx; dst[1] = gy; dst[2] = gz;
    } else {
        const int pt = m - 48;
        const int h = pt / 12, p = pt % 12;
        const float* src = row + 720;
        X = src[pt]; Y = src[144 + pt]; Z = src[288 + pt];
        float gx = R[0] * X + R[1] * Y + R[2] * Z + tr[0];
        float gy = R[3] * X + R[4] * Y + R[5] * Z + tr[1];
        float gz = R[6] * X + R[7] * Y + R[8] * Z + tr[2];
        if (p < 4) {
            float* dst = kpt + (size_t)n * 144 + h * 12 + p * 3;
            dst[0] = gx; dst[1] = gy; dst[2] = gz;
        } else {
            ushort_t* dst = vpt + (size_t)n * 288 + h * 24 + (p - 4) * 3;
            dst[0] = f2b(gx); dst[1] = f2b(gy); dst[2] = f2b(gz);
        }
    }
}

// ---------------------------------------------------------------------------
// attention with FUSED z-projection. One block (256 thr) per node.
// Phase 0 : stage z[n] (32x128 f32 -> bf16 LDS) + node-locals
// Phase 0b: waves 0-2 compute zp[32][44] = z_tile @ WcatT^T + bcat via MFMA
//           (B-fragments read directly from global WcatT, L2-resident 12KB)
// Phase 1 : logits (direct gather of k / k_pts)
// Phase 2 : parallel softmax
// Phase 3 : weighted sums (direct wave-coalesced gather of v / v_pts)
// Phase 4 : rotate back + norms
// LDS ~18.6KB -> 8 blocks/CU.
// ---------------------------------------------------------------------------
__global__ __launch_bounds__(256, 8) void attn_kernel(
    const float* __restrict__ q,           // proj_all (stride 1152, cols 0..191)
    const ushort_t* __restrict__ kbt,      // N x 192 bf16
    const ushort_t* __restrict__ vbt,      // N x 192 bf16
    const float* __restrict__ q_pts,       // N x 144 f32
    const float* __restrict__ kpt,         // N x 144 f32
    const ushort_t* __restrict__ vpt,      // N x 288 bf16
    const float* __restrict__ z,           // N x (32*128) f32
    const ushort_t* __restrict__ wcatT,    // 48 x 128 bf16
    const float* __restrict__ bcat,        // 44 f32
    const int*   __restrict__ eidx,
    const float* __restrict__ mask,
    const float* __restrict__ rot,
    const float* __restrict__ trans,
    const float* __restrict__ head_weights,
    float* __restrict__ catb)
{
    const int n   = blockIdx.x;
    const int tid = threadIdx.x;
    const int wave = tid >> 6;
    const int lane = tid & 63;

    __shared__ ushort_t zt[32][136];    // z tile bf16 (row 272B: 2-way free)
    __shared__ float zp[32][44];        // projected pair feats (b_pair|pair_z)
    __shared__ float q_s[192];
    __shared__ float qp_s[144];
    __shared__ float a_s[12][33];
    __shared__ float opt[288];          // h*24 + p*3 + x
    __shared__ int   idx_s[32];
    __shared__ float madd_s[32];
    __shared__ float R_s[9];
    __shared__ float t_s[3];
    __shared__ float hw_s[12];

    // ---- phase 0: stage z tile + reused node-locals ----
    {
        const int r = tid >> 3, seg = tid & 7;          // 32 rows x 8 segs of 16
        const float* zsrc = z + (size_t)n * 4096 + r * 128 + seg * 16;
        float4 v0 = *(const float4*)(zsrc);
        float4 v1 = *(const float4*)(zsrc + 4);
        float4 v2 = *(const float4*)(zsrc + 8);
        float4 v3 = *(const float4*)(zsrc + 12);
        ushort8 u0, u1;
        u0[0] = f2b(v0.x); u0[1] = f2b(v0.y); u0[2] = f2b(v0.z); u0[3] = f2b(v0.w);
        u0[4] = f2b(v1.x); u0[5] = f2b(v1.y); u0[6] = f2b(v1.z); u0[7] = f2b(v1.w);
        u1[0] = f2b(v2.x); u1[1] = f2b(v2.y); u1[2] = f2b(v2.z); u1[3] = f2b(v2.w);
        u1[4] = f2b(v3.x); u1[5] = f2b(v3.y); u1[6] = f2b(v3.z); u1[7] = f2b(v3.w);
        *(ushort8*)&zt[r][seg * 16]     = u0;
        *(ushort8*)&zt[r][seg * 16 + 8] = u1;
    }
    for (int i = tid; i < 192; i += 256) q_s[i]  = q[(size_t)n * 1152 + i];
    for (int i = tid; i < 144; i += 256) qp_s[i] = q_pts[(size_t)n * 144 + i];
    if (tid < 32) {
        const int ix = eidx[n * 32 + tid];
        idx_s[tid]  = ix;
        madd_s[tid] = 100000.0f * (mask[ix] - 1.0f);
    }
    if (tid >= 32 && tid < 41) R_s[tid - 32]  = rot[n * 9 + (tid - 32)];
    if (tid >= 41 && tid < 44) t_s[tid - 41]  = trans[n * 3 + (tid - 41)];
    if (tid >= 44 && tid < 56) {
        float x = head_weights[tid - 44];
        hw_s[tid - 44] = log1pf(__expf(x)) * 0.13608276348795434f; // softplus*sqrt(1/54)
    }
    __syncthreads();

    // ---- phase 0b: z-projection MFMA (waves 0..2; ntile = wave) ----
    if (wave < 3) {
        const int m16 = lane & 15;
        const int kof = (lane >> 4) * 8;
        f32x4 acc0 = (f32x4)0.0f, acc1 = (f32x4)0.0f;
        const ushort_t* wrow = wcatT + (wave * 16 + m16) * 128 + kof;
#pragma unroll
        for (int ks = 0; ks < 4; ++ks) {
            short8v b  = *(const short8v*)(wrow + ks * 32);
            short8v a0 = *(const short8v*)&zt[m16][ks * 32 + kof];
            short8v a1 = *(const short8v*)&zt[16 + m16][ks * 32 + kof];
            acc0 = __builtin_amdgcn_mfma_f32_16x16x32_bf16(a0, b, acc0, 0, 0, 0);
            acc1 = __builtin_amdgcn_mfma_f32_16x16x32_bf16(a1, b, acc1, 0, 0, 0);
        }
        const int col = wave * 16 + m16;
        if (col < 44) {
            const float bv = bcat[col];
            const int rb = (lane >> 4) * 4;
#pragma unroll
            for (int r = 0; r < 4; ++r) {
                zp[rb + r][col]      = acc0[r] + bv;
                zp[16 + rb + r][col] = acc1[r] + bv;
            }
        }
    }
    __syncthreads();

    // ---- phase 1: logits, direct gather ----
    for (int t = tid; t < 384; t += 256) {
        const int h = t >> 5, j = t & 31;
        const int ix = idx_s[j];
        const ushort_t* kr = kbt + (size_t)ix * 192 + h * 16;
        ushort8 k0 = *(const ushort8*)(kr);
        ushort8 k1 = *(const ushort8*)(kr + 8);
        const float* kpr = kpt + (size_t)ix * 144 + h * 12;
        float4 p0 = *(const float4*)(kpr);
        float4 p1 = *(const float4*)(kpr + 4);
        float4 p2 = *(const float4*)(kpr + 8);

        const float* qh = q_s + h * 16;
        float dot = 0.0f;
#pragma unroll
        for (int c = 0; c < 8; ++c) dot += qh[c] * b2f(k0[c]);
#pragma unroll
        for (int c = 0; c < 8; ++c) dot += qh[8 + c] * b2f(k1[c]);

        const float* qp = qp_s + h * 12;
        float d, pt = 0.0f;
        d = qp[0]  - p0.x; pt += d * d;  d = qp[1]  - p0.y; pt += d * d;
        d = qp[2]  - p0.z; pt += d * d;  d = qp[3]  - p0.w; pt += d * d;
        d = qp[4]  - p1.x; pt += d * d;  d = qp[5]  - p1.y; pt += d * d;
        d = qp[6]  - p1.z; pt += d * d;  d = qp[7]  - p1.w; pt += d * d;
        d = qp[8]  - p2.x; pt += d * d;  d = qp[9]  - p2.y; pt += d * d;
        d = qp[10] - p2.z; pt += d * d;  d = qp[11] - p2.w; pt += d * d;

        a_s[h][j] = 0.14433756729740643f * dot
                  + 0.5773502691896258f * zp[j][h]
                  - 0.5f * hw_s[h] * pt
                  + madd_s[j];
    }
    __syncthreads();

    // ---- phase 2: parallel softmax (96 threads, 8-lane shuffle groups) ----
    if (tid < 96) {
        const int h = tid >> 3, g = tid & 7;
        float a0 = a_s[h][g * 4 + 0], a1 = a_s[h][g * 4 + 1];
        float a2 = a_s[h][g * 4 + 2], a3 = a_s[h][g * 4 + 3];
        float m = fmaxf(fmaxf(a0, a1), fmaxf(a2, a3));
        m = fmaxf(m, __shfl_xor(m, 1)); m = fmaxf(m, __shfl_xor(m, 2));
        m = fmaxf(m, __shfl_xor(m, 4));
        float e0 = __expf(a0 - m), e1 = __expf(a1 - m);
        float e2 = __expf(a2 - m), e3 = __expf(a3 - m);
        float s = e0 + e1 + e2 + e3;
        s += __shfl_xor(s, 1); s += __shfl_xor(s, 2); s += __shfl_xor(s, 4);
        const float inv = 1.0f / s;
        a_s[h][g * 4 + 0] = e0 * inv; a_s[h][g * 4 + 1] = e1 * inv;
        a_s[h][g * 4 + 2] = e2 * inv; a_s[h][g * 4 + 3] = e3 * inv;
    }
    __syncthreads();

    // ---- phase 3: weighted sums, wave-coalesced direct reads ----
    float* catn = catb + (size_t)n * 960;
    if (tid < 48) {                      // o: (h, c-quad)
        const int h = tid >> 2, cq = tid & 3;
        const ushort_t* base = vbt + h * 16 + cq * 4;
        float s0 = 0, s1 = 0, s2 = 0, s3 = 0;
#pragma unroll 8
        for (int j = 0; j < 32; ++j) {
            const int ix = idx_s[j];
            const float aj = a_s[h][j];
            ushort4v v = *(const ushort4v*)(base + (size_t)ix * 192);
            s0 += aj * b2f(v[0]); s1 += aj * b2f(v[1]);
            s2 += aj * b2f(v[2]); s3 += aj * b2f(v[3]);
        }
        float4 o = { s0, s1, s2, s3 };
        *(float4*)&catn[h * 16 + cq * 4] = o;
    } else if (tid < 120) {              // o_pt: (h, quad of 24)
        const int u = tid - 48;
        const int h = u / 6, rq = u % 6;
        const ushort_t* base = vpt + h * 24 + rq * 4;
        float s0 = 0, s1 = 0, s2 = 0, s3 = 0;
#pragma unroll 8
        for (int j = 0; j < 32; ++j) {
            const int ix = idx_s[j];
            const float aj = a_s[h][j];
            ushort4v v = *(const ushort4v*)(base + (size_t)ix * 288);
            s0 += aj * b2f(v[0]); s1 += aj * b2f(v[1]);
            s2 += aj * b2f(v[2]); s3 += aj * b2f(v[3]);
        }
        float* od = opt + h * 24 + rq * 4;
        od[0] = s0; od[1] = s1; od[2] = s2; od[3] = s3;
    } else if (tid < 216) {              // o_pair: (h, c-quad of 32)
        const int u = tid - 120;
        const int h = u >> 3, cq = u & 7;
        f32x4 acc = (f32x4)0.0f;
#pragma unroll 8
        for (int j = 0; j < 32; ++j) {
            const float aj = a_s[h][j];
            f32x4 zv = *(const f32x4*)&zp[j][12 + cq * 4];
            acc += aj * zv;
        }
        *(f32x4*)&catn[576 + h * 32 + cq * 4] = acc;
    }
    __syncthreads();

    // ---- phase 4: rotate back + norms ----
    if (tid < 96) {
        const int h = tid >> 3, p = tid & 7;
        const float* ob = opt + h * 24 + p * 3;
        float gx = ob[0] - t_s[0];
        float gy = ob[1] - t_s[1];
        float gz = ob[2] - t_s[2];
        float lx = R_s[0] * gx + R_s[3] * gy + R_s[6] * gz;
        float ly = R_s[1] * gx + R_s[4] * gy + R_s[7] * gz;
        float lz = R_s[2] * gx + R_s[5] * gy + R_s[8] * gz;
        const int hp = h * 8 + p;
        catn[192 + hp] = lx;
        catn[288 + hp] = ly;
        catn[384 + hp] = lz;
        catn[480 + hp] = sqrtf(lx * lx + ly * ly + lz * lz + 1e-8f);
    }
}

// ---------------------------------------------------------------------------
extern "C" void kernel_launch(void* const* d_in, const int* in_sizes, int n_in,
                              void* d_out, int out_size, void* d_ws, size_t ws_size,
                              hipStream_t stream)
{
    const float* s     = (const float*)d_in[0];
    const float* z     = (const float*)d_in[1];
    const int*   eidx  = (const int*)  d_in[2];
    const float* rot   = (const float*)d_in[3];
    const float* trans = (const float*)d_in[4];
    const float* mask  = (const float*)d_in[5];
    const float* w_q   = (const float*)d_in[6];
    const float* b_q   = (const float*)d_in[7];
    const float* w_kv  = (const float*)d_in[8];
    const float* b_kv  = (const float*)d_in[9];
    const float* w_qp  = (const float*)d_in[10];
    const float* b_qp  = (const float*)d_in[11];
    const float* w_kvp = (const float*)d_in[12];
    const float* b_kvp = (const float*)d_in[13];
    const float* w_b   = (const float*)d_in[14];
    const float* b_b   = (const float*)d_in[15];
    const float* w_dz  = (const float*)d_in[16];
    const float* b_dz  = (const float*)d_in[17];
    const float* hw    = (const float*)d_in[18];
    const float* w_out = (const float*)d_in[19];
    const float* b_out = (const float*)d_in[20];
    float* out = (float*)d_out;

    float* ws = (float*)d_ws;
    size_t off = 0;
    float* proj_all = ws + off; off += (size_t)N_NODES * 1152;
    float* q_pts    = ws + off; off += (size_t)N_NODES * 144;
    float* kpt      = ws + off; off += (size_t)N_NODES * 144;
    ushort_t* vpt   = (ushort_t*)(ws + off); off += (size_t)N_NODES * 144;
    ushort_t* kbt   = (ushort_t*)(ws + off); off += (size_t)N_NODES * 96;
    ushort_t* vbt   = (ushort_t*)(ws + off); off += (size_t)N_NODES * 96;
    float* catb     = ws + off; off += (size_t)N_NODES * 960;
    float* Wall     = ws + off; off += (size_t)384 * 1152;
    float* ball     = ws + off; off += 1152;
    ushort_t* WcatT = (ushort_t*)(ws + off); off += (48 * 128) / 2;
    float* bcat     = ws + off; off += 44;

    // 1) fused s-projection (q|kv|qp|kvp) via MFMA (128x128 tiles)
    build_wall<<<(384 * 1152 + 255) / 256, 256, 0, stream>>>(
        w_q, b_q, w_kv, b_kv, w_qp, b_qp, w_kvp, b_kvp, Wall, ball);
    gemm_bf16<<<dim3(N_NODES / 128, 9), 256, 0, stream>>>(s, Wall, ball, proj_all,
                                                          N_NODES, 384, 1152);

    // 2) pair-projection weights (transposed bf16, consumed inside attn)
    build_wcatT<<<24, 256, 0, stream>>>(w_b, b_b, w_dz, b_dz, WcatT, bcat);

    // 3) gather tables: point transforms + bf16 conversions
    prep_tables<<<(N_NODES * 576 + 255) / 256, 256, 0, stream>>>(
        proj_all, rot, trans, q_pts, kpt, vpt, kbt, vbt);

    // 4) attention with fused z-projection
    attn_kernel<<<N_NODES, 256, 0, stream>>>(
        proj_all, kbt, vbt, q_pts, kpt, vpt, z, WcatT, bcat,
        eidx, mask, rot, trans, hw, catb);

    // 5) output projection via MFMA (64x64 tiles: 768 blocks)
    gemm_bf16_64<<<dim3(N_NODES / 64, 6), 256, 0, stream>>>(catb, w_out, b_out, out,
                                                            N_NODES, 960, 384);
}

// Round 7
// 188.136 us; speedup vs baseline: 3.1370x; 1.0767x over previous
//
#include <hip/hip_runtime.h>
#include <hip/hip_bf16.h>
#include <math.h>

#define N_NODES 8192
#define KNN 32

typedef unsigned short ushort_t;
typedef ushort_t ushort8 __attribute__((ext_vector_type(8)));
typedef ushort_t ushort4v __attribute__((ext_vector_type(4)));
typedef short short8v __attribute__((ext_vector_type(8)));
typedef float f32x4 __attribute__((ext_vector_type(4)));

static __device__ __forceinline__ float b2f(ushort_t u) {
    union { float f; unsigned int i; } v; v.i = ((unsigned int)u) << 16; return v.f;
}
static __device__ __forceinline__ ushort_t f2b(float f) {
    __hip_bfloat16 h = __float2bfloat16(f);
    return *(ushort_t*)&h;
}

// ---------------------------------------------------------------------------
// bf16 MFMA GEMM, 128x128 tile, XCD-affine swizzle (s-projection).
// Grid: 1-D, (M/128)*ncol blocks; requires (M/128)%8==0, P%128==0.
// id -> xcd=id&7, q=id>>3; row=(q/ncol)*8+xcd (col-tiles of one row-panel are
// consecutive on one XCD -> A panel stays L2-resident).
// ---------------------------------------------------------------------------
__global__ __launch_bounds__(256) void gemm_bf16(
    const float* __restrict__ A, const float* __restrict__ W,
    const float* __restrict__ bias, float* __restrict__ C,
    int M, int K, int P)
{
    __shared__ ushort_t As[128][40];   // [m][k]
    __shared__ ushort_t Bs[128][40];   // [n][k]

    const int tid  = threadIdx.x;
    const int ncol = P >> 7;
    const int id   = blockIdx.x;
    const int xcd  = id & 7;
    const int qq   = id >> 3;
    const int row0 = ((qq / ncol) * 8 + xcd) * 128;
    const int col0 = (qq % ncol) * 128;

    const int wave = tid >> 6;
    const int lane = tid & 63;
    const int wm = (wave >> 1) * 64;
    const int wn = (wave & 1) * 64;
    const int m16 = lane & 15;
    const int kof = (lane >> 4) * 8;

    const int a_row = tid >> 1;
    const int a_kq  = (tid & 1) * 16;
    const int b_n  = tid >> 1;
    const int b_kq = (tid & 1) * 16;

    f32x4 acc[4][4];
#pragma unroll
    for (int i = 0; i < 4; ++i)
#pragma unroll
        for (int j = 0; j < 4; ++j) acc[i][j] = (f32x4)0.0f;

    for (int k0 = 0; k0 < K; k0 += 32) {
        {
            const float* ap = A + (size_t)(row0 + a_row) * K + (k0 + a_kq);
            float4 v0 = *(const float4*)(ap);
            float4 v1 = *(const float4*)(ap + 4);
            float4 v2 = *(const float4*)(ap + 8);
            float4 v3 = *(const float4*)(ap + 12);
            ushort8 u0, u1;
            u0[0] = f2b(v0.x); u0[1] = f2b(v0.y); u0[2] = f2b(v0.z); u0[3] = f2b(v0.w);
            u0[4] = f2b(v1.x); u0[5] = f2b(v1.y); u0[6] = f2b(v1.z); u0[7] = f2b(v1.w);
            u1[0] = f2b(v2.x); u1[1] = f2b(v2.y); u1[2] = f2b(v2.z); u1[3] = f2b(v2.w);
            u1[4] = f2b(v3.x); u1[5] = f2b(v3.y); u1[6] = f2b(v3.z); u1[7] = f2b(v3.w);
            *(ushort8*)&As[a_row][a_kq]     = u0;
            *(ushort8*)&As[a_row][a_kq + 8] = u1;
        }
        {
            const int col = col0 + b_n;
            const float* wp = W + (size_t)(k0 + b_kq) * P + col;
            ushort8 u0, u1;
#pragma unroll
            for (int i = 0; i < 8; ++i) { u0[i] = f2b(*wp); wp += P; }
#pragma unroll
            for (int i = 0; i < 8; ++i) { u1[i] = f2b(*wp); wp += P; }
            *(ushort8*)&Bs[b_n][b_kq]     = u0;
            *(ushort8*)&Bs[b_n][b_kq + 8] = u1;
        }
        __syncthreads();

        short8v a[4], b[4];
#pragma unroll
        for (int mb = 0; mb < 4; ++mb)
            a[mb] = *(const short8v*)&As[wm + mb * 16 + m16][kof];
#pragma unroll
        for (int nb = 0; nb < 4; ++nb)
            b[nb] = *(const short8v*)&Bs[wn + nb * 16 + m16][kof];
#pragma unroll
        for (int mb = 0; mb < 4; ++mb)
#pragma unroll
            for (int nb = 0; nb < 4; ++nb)
                acc[mb][nb] = __builtin_amdgcn_mfma_f32_16x16x32_bf16(
                    a[mb], b[nb], acc[mb][nb], 0, 0, 0);
        __syncthreads();
    }

    const int r_base = row0 + wm + (lane >> 4) * 4;
#pragma unroll
    for (int nb = 0; nb < 4; ++nb) {
        const int col = col0 + wn + nb * 16 + m16;
        const float bv = bias[col];
#pragma unroll
        for (int mb = 0; mb < 4; ++mb) {
#pragma unroll
            for (int r = 0; r < 4; ++r) {
                C[(size_t)(r_base + mb * 16 + r) * P + col] = acc[mb][nb][r] + bv;
            }
        }
    }
}

// ---------------------------------------------------------------------------
// out-GEMM: A already bf16 (catb), 64x64 tile, XCD-affine swizzle.
// Grid: (M/64)*ncol; (M/64)%8==0, P%64==0. C fp32 + bias.
// ---------------------------------------------------------------------------
__global__ __launch_bounds__(256) void gemm_out(
    const ushort_t* __restrict__ A, const float* __restrict__ W,
    const float* __restrict__ bias, float* __restrict__ C,
    int M, int K, int P)
{
    __shared__ ushort_t As[64][40];
    __shared__ ushort_t Bs[64][40];

    const int tid  = threadIdx.x;
    const int ncol = P >> 6;
    const int id   = blockIdx.x;
    const int xcd  = id & 7;
    const int qq   = id >> 3;
    const int row0 = ((qq / ncol) * 8 + xcd) * 64;
    const int col0 = (qq % ncol) * 64;

    const int wave = tid >> 6;
    const int lane = tid & 63;
    const int wm = (wave >> 1) * 32;
    const int wn = (wave & 1) * 32;
    const int m16 = lane & 15;
    const int kof = (lane >> 4) * 8;

    const int a_row = tid >> 2;
    const int a_kq  = (tid & 3) * 8;

    f32x4 acc[2][2];
#pragma unroll
    for (int i = 0; i < 2; ++i)
#pragma unroll
        for (int j = 0; j < 2; ++j) acc[i][j] = (f32x4)0.0f;

    for (int k0 = 0; k0 < K; k0 += 32) {
        *(ushort8*)&As[a_row][a_kq] =
            *(const ushort8*)(A + (size_t)(row0 + a_row) * K + (k0 + a_kq));
        {
            const int col = col0 + a_row;
            const float* wp = W + (size_t)(k0 + a_kq) * P + col;
            ushort8 u;
#pragma unroll
            for (int i = 0; i < 8; ++i) { u[i] = f2b(*wp); wp += P; }
            *(ushort8*)&Bs[a_row][a_kq] = u;
        }
        __syncthreads();

        short8v a[2], b[2];
#pragma unroll
        for (int mb = 0; mb < 2; ++mb)
            a[mb] = *(const short8v*)&As[wm + mb * 16 + m16][kof];
#pragma unroll
        for (int nb = 0; nb < 2; ++nb)
            b[nb] = *(const short8v*)&Bs[wn + nb * 16 + m16][kof];
#pragma unroll
        for (int mb = 0; mb < 2; ++mb)
#pragma unroll
            for (int nb = 0; nb < 2; ++nb)
                acc[mb][nb] = __builtin_amdgcn_mfma_f32_16x16x32_bf16(
                    a[mb], b[nb], acc[mb][nb], 0, 0, 0);
        __syncthreads();
    }

    const int r_base = row0 + wm + (lane >> 4) * 4;
#pragma unroll
    for (int nb = 0; nb < 2; ++nb) {
        const int col = col0 + wn + nb * 16 + m16;
        const float bv = bias[col];
#pragma unroll
        for (int mb = 0; mb < 2; ++mb) {
#pragma unroll
            for (int r = 0; r < 4; ++r) {
                C[(size_t)(r_base + mb * 16 + r) * P + col] = acc[mb][nb][r] + bv;
            }
        }
    }
}

// ---------------------------------------------------------------------------
// z-projection GEMM: zph[262144][48 bf16] = z[262144][128] @ Wcat[128][44]+bcat
// Streaming; 64x64 tile (cols >=44 masked); bf16 output, row stride 48.
// ---------------------------------------------------------------------------
__global__ __launch_bounds__(256) void gemm_zproj(
    const float* __restrict__ Z, const float* __restrict__ Wc,
    const float* __restrict__ bc, ushort_t* __restrict__ zph)
{
    __shared__ ushort_t As[64][40];
    __shared__ ushort_t Bs[64][40];

    const int tid  = threadIdx.x;
    const int row0 = blockIdx.x * 64;

    const int wave = tid >> 6;
    const int lane = tid & 63;
    const int wm = (wave >> 1) * 32;
    const int wn = (wave & 1) * 32;
    const int m16 = lane & 15;
    const int kof = (lane >> 4) * 8;

    const int a_row = tid >> 2;
    const int a_kq  = (tid & 3) * 8;

    f32x4 acc[2][2];
#pragma unroll
    for (int i = 0; i < 2; ++i)
#pragma unroll
        for (int j = 0; j < 2; ++j) acc[i][j] = (f32x4)0.0f;

    for (int k0 = 0; k0 < 128; k0 += 32) {
        {
            const float* ap = Z + (size_t)(row0 + a_row) * 128 + (k0 + a_kq);
            float4 v0 = *(const float4*)(ap);
            float4 v1 = *(const float4*)(ap + 4);
            ushort8 u;
            u[0] = f2b(v0.x); u[1] = f2b(v0.y); u[2] = f2b(v0.z); u[3] = f2b(v0.w);
            u[4] = f2b(v1.x); u[5] = f2b(v1.y); u[6] = f2b(v1.z); u[7] = f2b(v1.w);
            *(ushort8*)&As[a_row][a_kq] = u;
        }
        {
            const int col = a_row;
            ushort8 u;
            if (col < 44) {
                const float* wp = Wc + (size_t)(k0 + a_kq) * 44 + col;
#pragma unroll
                for (int i = 0; i < 8; ++i) { u[i] = f2b(*wp); wp += 44; }
            } else {
                u = (ushort8)0;
            }
            *(ushort8*)&Bs[a_row][a_kq] = u;
        }
        __syncthreads();

        short8v a[2], b[2];
#pragma unroll
        for (int mb = 0; mb < 2; ++mb)
            a[mb] = *(const short8v*)&As[wm + mb * 16 + m16][kof];
#pragma unroll
        for (int nb = 0; nb < 2; ++nb)
            b[nb] = *(const short8v*)&Bs[wn + nb * 16 + m16][kof];
#pragma unroll
        for (int mb = 0; mb < 2; ++mb)
#pragma unroll
            for (int nb = 0; nb < 2; ++nb)
                acc[mb][nb] = __builtin_amdgcn_mfma_f32_16x16x32_bf16(
                    a[mb], b[nb], acc[mb][nb], 0, 0, 0);
        __syncthreads();
    }

    const int r_base = row0 + wm + (lane >> 4) * 4;
#pragma unroll
    for (int nb = 0; nb < 2; ++nb) {
        const int col = wn + nb * 16 + m16;
        if (col >= 44) continue;
        const float bv = bc[col];
#pragma unroll
        for (int mb = 0; mb < 2; ++mb) {
#pragma unroll
            for (int r = 0; r < 4; ++r) {
                zph[(size_t)(r_base + mb * 16 + r) * 48 + col] = f2b(acc[mb][nb][r] + bv);
            }
        }
    }
}

// Build Wall (384 x 1152) = [w_q | w_kv | w_qp | w_kvp], ball(1152)
__global__ void build_wall(const float* __restrict__ wq,  const float* __restrict__ bq,
                           const float* __restrict__ wkv, const float* __restrict__ bkv,
                           const float* __restrict__ wqp, const float* __restrict__ bqp,
                           const float* __restrict__ wkvp,const float* __restrict__ bkvp,
                           float* __restrict__ Wall, float* __restrict__ ball)
{
    int t = blockIdx.x * 256 + threadIdx.x;
    if (t < 384 * 1152) {
        int c = t / 1152, j = t % 1152;
        float v;
        if      (j < 192)  v = wq  [c * 192 + j];
        else if (j < 576)  v = wkv [c * 384 + (j - 192)];
        else if (j < 720)  v = wqp [c * 144 + (j - 576)];
        else               v = wkvp[c * 432 + (j - 720)];
        Wall[t] = v;
    }
    if (t < 1152) {
        float v;
        if      (t < 192)  v = bq[t];
        else if (t < 576)  v = bkv[t - 192];
        else if (t < 720)  v = bqp[t - 576];
        else               v = bkvp[t - 720];
        ball[t] = v;
    }
}

// Concatenate w_b (128x12) | w_dz (128x32) -> Wcat (128x44) fp32
__global__ void build_wcat(const float* __restrict__ wb, const float* __restrict__ bb,
                           const float* __restrict__ wdz, const float* __restrict__ bdz,
                           float* __restrict__ Wcat, float* __restrict__ bcat)
{
    int t = blockIdx.x * 256 + threadIdx.x;
    if (t < 128 * 44) {
        int c = t / 44, j = t % 44;
        Wcat[t] = (j < 12) ? wb[c * 12 + j] : wdz[c * 32 + (j - 12)];
    }
    if (t < 44) bcat[t] = (t < 12) ? bb[t] : bdz[t - 12];
}

// ---------------------------------------------------------------------------
// prep_tables: per node, 576 tasks (unchanged)
// ---------------------------------------------------------------------------
__global__ void prep_tables(const float* __restrict__ proj_all,
                            const float* __restrict__ rot,
                            const float* __restrict__ trans,
                            float* __restrict__ q_pts,
                            float* __restrict__ kpt,
                            ushort_t* __restrict__ vpt,
                            ushort_t* __restrict__ kbt,
                            ushort_t* __restrict__ vbt)
{
    int t = blockIdx.x * 256 + threadIdx.x;
    if (t >= N_NODES * 576) return;
    const int n = t / 576;
    const int m = t % 576;
    const float* row = proj_all + (size_t)n * 1152;

    if (m >= 192) {
        const int c0 = m - 192;
        const int h = c0 >> 5, c = c0 & 31;
        ushort_t v = f2b(row[192 + c0]);
        if (c < 16) kbt[(size_t)n * 192 + h * 16 + c] = v;
        else        vbt[(size_t)n * 192 + h * 16 + (c - 16)] = v;
        return;
    }

    const float* R  = rot + n * 9;
    const float* tr = trans + n * 3;
    float X, Y, Z;
    if (m < 48) {
        const float* src = row + 576;
        X = src[m]; Y = src[48 + m]; Z = src[96 + m];
        float gx = R[0] * X + R[1] * Y + R[2] * Z + tr[0];
        float gy = R[3] * X + R[4] * Y + R[5] * Z + tr[1];
        float gz = R[6] * X + R[7] * Y + R[8] * Z + tr[2];
        const int h = m >> 2, p = m & 3;
        float* dst = q_pts + (size_t)n * 144 + h * 12 + p * 3;
        dst[0] = gx; dst[1] = gy; dst[2] = gz;
    } else {
        const int pt = m - 48;
        const int h = pt / 12, p = pt % 12;
        const float* src = row + 720;
        X = src[pt]; Y = src[144 + pt]; Z = src[288 + pt];
        float gx = R[0] * X + R[1] * Y + R[2] * Z + tr[0];
        float gy = R[3] * X + R[4] * Y + R[5] * Z + tr[1];
        float gz = R[6] * X + R[7] * Y + R[8] * Z + tr[2];
        if (p < 4) {
            float* dst = kpt + (size_t)n * 144 + h * 12 + p * 3;
            dst[0] = gx; dst[1] = gy; dst[2] = gz;
        } else {
            ushort_t* dst = vpt + (size_t)n * 288 + h * 24 + (p - 4) * 3;
            dst[0] = f2b(gx); dst[1] = f2b(gy); dst[2] = f2b(gz);
        }
    }
}

// ---------------------------------------------------------------------------
// attention (round-4 de-staged structure): one block (256 thr) per node.
// zproj read as bf16 (stride-48 rows) into LDS; catb written as bf16.
// ---------------------------------------------------------------------------
__global__ __launch_bounds__(256, 8) void attn_kernel(
    const float* __restrict__ q,           // proj_all (stride 1152, cols 0..191)
    const ushort_t* __restrict__ kbt,      // N x 192 bf16
    const ushort_t* __restrict__ vbt,      // N x 192 bf16
    const float* __restrict__ q_pts,       // N x 144 f32
    const float* __restrict__ kpt,         // N x 144 f32
    const ushort_t* __restrict__ vpt,      // N x 288 bf16
    const ushort_t* __restrict__ zph,      // (N*K) x 48 bf16 (44 valid)
    const int*   __restrict__ eidx,
    const float* __restrict__ mask,
    const float* __restrict__ rot,
    const float* __restrict__ trans,
    const float* __restrict__ head_weights,
    ushort_t* __restrict__ catb)           // N x 960 bf16
{
    const int n   = blockIdx.x;
    const int tid = threadIdx.x;

    __shared__ ushort_t zp[32][48];     // 3072B
    __shared__ float q_s[192];
    __shared__ float qp_s[144];
    __shared__ float a_s[12][33];
    __shared__ float opt[288];          // h*24 + p*3 + x
    __shared__ int   idx_s[32];
    __shared__ float madd_s[32];
    __shared__ float R_s[9];
    __shared__ float t_s[3];
    __shared__ float hw_s[12];

    // ---- phase 0: stage reused data ----
    for (int i = tid; i < 192; i += 256) q_s[i]  = q[(size_t)n * 1152 + i];
    for (int i = tid; i < 144; i += 256) qp_s[i] = q_pts[(size_t)n * 144 + i];
    if (tid < 32) {
        const int ix = eidx[n * 32 + tid];
        idx_s[tid]  = ix;
        madd_s[tid] = 100000.0f * (mask[ix] - 1.0f);
    }
    if (tid >= 32 && tid < 41) R_s[tid - 32]  = rot[n * 9 + (tid - 32)];
    if (tid >= 41 && tid < 44) t_s[tid - 41]  = trans[n * 3 + (tid - 41)];
    if (tid >= 44 && tid < 56) {
        float x = head_weights[tid - 44];
        hw_s[tid - 44] = log1pf(__expf(x)) * 0.13608276348795434f; // softplus*sqrt(1/54)
    }
    if (tid < 192) {                    // zp: 32 rows x 6 chunks of 8 ushorts
        const int r = tid / 6, sg = tid % 6;
        *(ushort8*)&zp[r][sg * 8] =
            *(const ushort8*)(zph + ((size_t)n * 32 + r) * 48 + sg * 8);
    }
    __syncthreads();

    // ---- phase 1: logits, direct gather ----
    for (int t = tid; t < 384; t += 256) {
        const int h = t >> 5, j = t & 31;
        const int ix = idx_s[j];
        const ushort_t* kr = kbt + (size_t)ix * 192 + h * 16;
        ushort8 k0 = *(const ushort8*)(kr);
        ushort8 k1 = *(const ushort8*)(kr + 8);
        const float* kpr = kpt + (size_t)ix * 144 + h * 12;
        float4 p0 = *(const float4*)(kpr);
        float4 p1 = *(const float4*)(kpr + 4);
        float4 p2 = *(const float4*)(kpr + 8);

        const float* qh = q_s + h * 16;
        float dot = 0.0f;
#pragma unroll
        for (int c = 0; c < 8; ++c) dot += qh[c] * b2f(k0[c]);
#pragma unroll
        for (int c = 0; c < 8; ++c) dot += qh[8 + c] * b2f(k1[c]);

        const float* qp = qp_s + h * 12;
        float d, pt = 0.0f;
        d = qp[0]  - p0.x; pt += d * d;  d = qp[1]  - p0.y; pt += d * d;
        d = qp[2]  - p0.z; pt += d * d;  d = qp[3]  - p0.w; pt += d * d;
        d = qp[4]  - p1.x; pt += d * d;  d = qp[5]  - p1.y; pt += d * d;
        d = qp[6]  - p1.z; pt += d * d;  d = qp[7]  - p1.w; pt += d * d;
        d = qp[8]  - p2.x; pt += d * d;  d = qp[9]  - p2.y; pt += d * d;
        d = qp[10] - p2.z; pt += d * d;  d = qp[11] - p2.w; pt += d * d;

        a_s[h][j] = 0.14433756729740643f * dot
                  + 0.5773502691896258f * b2f(zp[j][h])
                  - 0.5f * hw_s[h] * pt
                  + madd_s[j];
    }
    __syncthreads();

    // ---- phase 2: parallel softmax (96 threads, 8-lane shuffle groups) ----
    if (tid < 96) {
        const int h = tid >> 3, g = tid & 7;
        float a0 = a_s[h][g * 4 + 0], a1 = a_s[h][g * 4 + 1];
        float a2 = a_s[h][g * 4 + 2], a3 = a_s[h][g * 4 + 3];
        float m = fmaxf(fmaxf(a0, a1), fmaxf(a2, a3));
        m = fmaxf(m, __shfl_xor(m, 1)); m = fmaxf(m, __shfl_xor(m, 2));
        m = fmaxf(m, __shfl_xor(m, 4));
        float e0 = __expf(a0 - m), e1 = __expf(a1 - m);
        float e2 = __expf(a2 - m), e3 = __expf(a3 - m);
        float s = e0 + e1 + e2 + e3;
        s += __shfl_xor(s, 1); s += __shfl_xor(s, 2); s += __shfl_xor(s, 4);
        const float inv = 1.0f / s;
        a_s[h][g * 4 + 0] = e0 * inv; a_s[h][g * 4 + 1] = e1 * inv;
        a_s[h][g * 4 + 2] = e2 * inv; a_s[h][g * 4 + 3] = e3 * inv;
    }
    __syncthreads();

    // ---- phase 3: weighted sums, wave-coalesced direct reads ----
    ushort_t* catn = catb + (size_t)n * 960;
    if (tid < 48) {                      // o: (h, c-quad)
        const int h = tid >> 2, cq = tid & 3;
        const ushort_t* base = vbt + h * 16 + cq * 4;
        float s0 = 0, s1 = 0, s2 = 0, s3 = 0;
#pragma unroll 8
        for (int j = 0; j < 32; ++j) {
            const int ix = idx_s[j];
            const float aj = a_s[h][j];
            ushort4v v = *(const ushort4v*)(base + (size_t)ix * 192);
            s0 += aj * b2f(v[0]); s1 += aj * b2f(v[1]);
            s2 += aj * b2f(v[2]); s3 += aj * b2f(v[3]);
        }
        ushort4v o = { f2b(s0), f2b(s1), f2b(s2), f2b(s3) };
        *(ushort4v*)&catn[h * 16 + cq * 4] = o;
    } else if (tid < 120) {              // o_pt: (h, quad of 24)
        const int u = tid - 48;
        const int h = u / 6, rq = u % 6;
        const ushort_t* base = vpt + h * 24 + rq * 4;
        float s0 = 0, s1 = 0, s2 = 0, s3 = 0;
#pragma unroll 8
        for (int j = 0; j < 32; ++j) {
            const int ix = idx_s[j];
            const float aj = a_s[h][j];
            ushort4v v = *(const ushort4v*)(base + (size_t)ix * 288);
            s0 += aj * b2f(v[0]); s1 += aj * b2f(v[1]);
            s2 += aj * b2f(v[2]); s3 += aj * b2f(v[3]);
        }
        float* od = opt + h * 24 + rq * 4;
        od[0] = s0; od[1] = s1; od[2] = s2; od[3] = s3;
    } else if (tid < 216) {              // o_pair: (h, c-quad of 32)
        const int u = tid - 120;
        const int h = u >> 3, cq = u & 7;
        float s0 = 0, s1 = 0, s2 = 0, s3 = 0;
#pragma unroll 8
        for (int j = 0; j < 32; ++j) {
            const float aj = a_s[h][j];
            ushort4v zv = *(const ushort4v*)&zp[j][12 + cq * 4];
            s0 += aj * b2f(zv[0]); s1 += aj * b2f(zv[1]);
            s2 += aj * b2f(zv[2]); s3 += aj * b2f(zv[3]);
        }
        ushort4v o = { f2b(s0), f2b(s1), f2b(s2), f2b(s3) };
        *(ushort4v*)&catn[576 + h * 32 + cq * 4] = o;
    }
    __syncthreads();

    // ---- phase 4: rotate back + norms ----
    if (tid < 96) {
        const int h = tid >> 3, p = tid & 7;
        const float* ob = opt + h * 24 + p * 3;
        float gx = ob[0] - t_s[0];
        float gy = ob[1] - t_s[1];
        float gz = ob[2] - t_s[2];
        float lx = R_s[0] * gx + R_s[3] * gy + R_s[6] * gz;
        float ly = R_s[1] * gx + R_s[4] * gy + R_s[7] * gz;
        float lz = R_s[2] * gx + R_s[5] * gy + R_s[8] * gz;
        const int hp = h * 8 + p;
        catn[192 + hp] = f2b(lx);
        catn[288 + hp] = f2b(ly);
        catn[384 + hp] = f2b(lz);
        catn[480 + hp] = f2b(sqrtf(lx * lx + ly * ly + lz * lz + 1e-8f));
    }
}

// ---------------------------------------------------------------------------
extern "C" void kernel_launch(void* const* d_in, const int* in_sizes, int n_in,
                              void* d_out, int out_size, void* d_ws, size_t ws_size,
                              hipStream_t stream)
{
    const float* s     = (const float*)d_in[0];
    const float* z     = (const float*)d_in[1];
    const int*   eidx  = (const int*)  d_in[2];
    const float* rot   = (const float*)d_in[3];
    const float* trans = (const float*)d_in[4];
    const float* mask  = (const float*)d_in[5];
    const float* w_q   = (const float*)d_in[6];
    const float* b_q   = (const float*)d_in[7];
    const float* w_kv  = (const float*)d_in[8];
    const float* b_kv  = (const float*)d_in[9];
    const float* w_qp  = (const float*)d_in[10];
    const float* b_qp  = (const float*)d_in[11];
    const float* w_kvp = (const float*)d_in[12];
    const float* b_kvp = (const float*)d_in[13];
    const float* w_b   = (const float*)d_in[14];
    const float* b_b   = (const float*)d_in[15];
    const float* w_dz  = (const float*)d_in[16];
    const float* b_dz  = (const float*)d_in[17];
    const float* hw    = (const float*)d_in[18];
    const float* w_out = (const float*)d_in[19];
    const float* b_out = (const float*)d_in[20];
    float* out = (float*)d_out;

    float* ws = (float*)d_ws;
    size_t off = 0;
    float* proj_all = ws + off; off += (size_t)N_NODES * 1152;
    float* q_pts    = ws + off; off += (size_t)N_NODES * 144;
    float* kpt      = ws + off; off += (size_t)N_NODES * 144;
    ushort_t* vpt   = (ushort_t*)(ws + off); off += (size_t)N_NODES * 144;
    ushort_t* kbt   = (ushort_t*)(ws + off); off += (size_t)N_NODES * 96;
    ushort_t* vbt   = (ushort_t*)(ws + off); off += (size_t)N_NODES * 96;
    ushort_t* zph   = (ushort_t*)(ws + off); off += (size_t)N_NODES * KNN * 24; // 48 bf16
    ushort_t* catb  = (ushort_t*)(ws + off); off += (size_t)N_NODES * 480;      // 960 bf16
    float* Wall     = ws + off; off += (size_t)384 * 1152;
    float* ball     = ws + off; off += 1152;
    float* Wcat     = ws + off; off += 128 * 44;
    float* bcat     = ws + off; off += 44;

    // 1) fused s-projection (q|kv|qp|kvp) via MFMA, XCD-affine swizzle
    build_wall<<<(384 * 1152 + 255) / 256, 256, 0, stream>>>(
        w_q, b_q, w_kv, b_kv, w_qp, b_qp, w_kvp, b_kvp, Wall, ball);
    gemm_bf16<<<(N_NODES / 128) * 9, 256, 0, stream>>>(s, Wall, ball, proj_all,
                                                       N_NODES, 384, 1152);

    // 2) z-projection -> bf16 zph (streaming)
    build_wcat<<<23, 256, 0, stream>>>(w_b, b_b, w_dz, b_dz, Wcat, bcat);
    gemm_zproj<<<(N_NODES * KNN) / 64, 256, 0, stream>>>(z, Wcat, bcat, zph);

    // 3) gather tables: point transforms + bf16 conversions
    prep_tables<<<(N_NODES * 576 + 255) / 256, 256, 0, stream>>>(
        proj_all, rot, trans, q_pts, kpt, vpt, kbt, vbt);

    // 4) attention (de-staged, bf16 zproj in, bf16 catb out)
    attn_kernel<<<N_NODES, 256, 0, stream>>>(
        proj_all, kbt, vbt, q_pts, kpt, vpt, zph, eidx, mask, rot, trans, hw, catb);

    // 5) output projection (bf16 A), XCD-affine swizzle
    gemm_out<<<(N_NODES / 64) * 6, 256, 0, stream>>>(catb, w_out, b_out, out,
                                                     N_NODES, 960, 384);
}

// Round 9
// 158.360 us; speedup vs baseline: 3.7268x; 1.1880x over previous
//
#include <hip/hip_runtime.h>
#include <hip/hip_bf16.h>
#include <math.h>

#define N_NODES 8192
#define KNN 32

typedef unsigned short ushort_t;
typedef ushort_t ushort8 __attribute__((ext_vector_type(8)));
typedef ushort_t ushort4v __attribute__((ext_vector_type(4)));
typedef short short8v __attribute__((ext_vector_type(8)));
typedef float f32x4 __attribute__((ext_vector_type(4)));

static __device__ __forceinline__ float b2f(ushort_t u) {
    union { float f; unsigned int i; } v; v.i = ((unsigned int)u) << 16; return v.f;
}
static __device__ __forceinline__ ushort_t f2b(float f) {
    __hip_bfloat16 h = __float2bfloat16(f);
    return *(ushort_t*)&h;
}

// ---------------------------------------------------------------------------
// build_weights: one launch producing all pre-transposed bf16 weight tables.
//  WallT [1152][384]  = [w_q|w_kv|w_qp|w_kvp]^T   (bf16)
//  ball  [1152]  fp32
//  WcatT [64][128]    = [w_b|w_dz]^T, rows>=44 zero (bf16)
//  bcat  [44]    fp32
//  WoutT [384][960]   = w_out^T (bf16)
// ---------------------------------------------------------------------------
#define N_WALLT (1152 * 384)
#define N_WCATT (64 * 128)
#define N_WOUTT (384 * 960)
__global__ void build_weights(
    const float* __restrict__ wq,  const float* __restrict__ bq,
    const float* __restrict__ wkv, const float* __restrict__ bkv,
    const float* __restrict__ wqp, const float* __restrict__ bqp,
    const float* __restrict__ wkvp,const float* __restrict__ bkvp,
    const float* __restrict__ wb,  const float* __restrict__ bb,
    const float* __restrict__ wdz, const float* __restrict__ bdz,
    const float* __restrict__ wout,
    ushort_t* __restrict__ WallT, float* __restrict__ ball,
    ushort_t* __restrict__ WcatT, float* __restrict__ bcat,
    ushort_t* __restrict__ WoutT)
{
    int t = blockIdx.x * 256 + threadIdx.x;
    if (t < N_WALLT) {
        const int p = t / 384, k = t % 384;
        float v;
        if      (p < 192) v = wq  [k * 192 + p];
        else if (p < 576) v = wkv [k * 384 + (p - 192)];
        else if (p < 720) v = wqp [k * 144 + (p - 576)];
        else              v = wkvp[k * 432 + (p - 720)];
        WallT[t] = f2b(v);
    } else if (t < N_WALLT + N_WCATT) {
        const int u = t - N_WALLT;
        const int j = u >> 7, c = u & 127;
        float v = (j < 12) ? wb[c * 12 + j] : (j < 44 ? wdz[c * 32 + (j - 12)] : 0.0f);
        WcatT[u] = f2b(v);
    } else if (t < N_WALLT + N_WCATT + N_WOUTT) {
        const int u = t - N_WALLT - N_WCATT;
        const int p = u / 960, k = u % 960;
        WoutT[u] = f2b(wout[k * 384 + p]);
    } else {
        const int u = t - N_WALLT - N_WCATT - N_WOUTT;
        if (u < 1152) {
            float v;
            if      (u < 192)  v = bq[u];
            else if (u < 576)  v = bkv[u - 192];
            else if (u < 720)  v = bqp[u - 576];
            else               v = bkvp[u - 720];
            ball[u] = v;
        } else if (u < 1152 + 44) {
            const int w = u - 1152;
            bcat[w] = (w < 12) ? bb[w] : bdz[w - 12];
        }
    }
}
#define BW_TOTAL (N_WALLT + N_WCATT + N_WOUTT + 1152 + 44)

// ---------------------------------------------------------------------------
// s-projection GEMM, 128x128 tile, XCD-affine swizzle, SPLIT epilogue:
//   cols   0..191 -> qb  bf16 [n][192]
//   cols 192..575 -> kbt/vbt bf16 [n][192] (h*16+c split)
//   cols 576..1151-> praw fp32 [n][576]  (point coords, rotated later)
// ---------------------------------------------------------------------------
__global__ __launch_bounds__(256) void gemm_sproj(
    const float* __restrict__ A, const ushort_t* __restrict__ WT,
    const float* __restrict__ bias,
    ushort_t* __restrict__ qb, ushort_t* __restrict__ kbt,
    ushort_t* __restrict__ vbt, float* __restrict__ praw)
{
    __shared__ ushort_t As[128][40];   // [m][k]
    __shared__ ushort_t Bs[128][40];   // [n][k]

    const int tid  = threadIdx.x;
    const int ncol = 9;                        // 1152/128
    const int id   = blockIdx.x;
    const int xcd  = id & 7;
    const int qq   = id >> 3;
    const int row0 = ((qq / ncol) * 8 + xcd) * 128;
    const int col0 = (qq % ncol) * 128;
    const int K    = 384;

    const int wave = tid >> 6;
    const int lane = tid & 63;
    const int wm = (wave >> 1) * 64;
    const int wn = (wave & 1) * 64;
    const int m16 = lane & 15;
    const int kof = (lane >> 4) * 8;

    const int a_row = tid >> 1;
    const int a_kq  = (tid & 1) * 16;

    f32x4 acc[4][4];
#pragma unroll
    for (int i = 0; i < 4; ++i)
#pragma unroll
        for (int j = 0; j < 4; ++j) acc[i][j] = (f32x4)0.0f;

    for (int k0 = 0; k0 < K; k0 += 32) {
        {
            const float* ap = A + (size_t)(row0 + a_row) * K + (k0 + a_kq);
            float4 v0 = *(const float4*)(ap);
            float4 v1 = *(const float4*)(ap + 4);
            float4 v2 = *(const float4*)(ap + 8);
            float4 v3 = *(const float4*)(ap + 12);
            ushort8 u0, u1;
            u0[0] = f2b(v0.x); u0[1] = f2b(v0.y); u0[2] = f2b(v0.z); u0[3] = f2b(v0.w);
            u0[4] = f2b(v1.x); u0[5] = f2b(v1.y); u0[6] = f2b(v1.z); u0[7] = f2b(v1.w);
            u1[0] = f2b(v2.x); u1[1] = f2b(v2.y); u1[2] = f2b(v2.z); u1[3] = f2b(v2.w);
            u1[4] = f2b(v3.x); u1[5] = f2b(v3.y); u1[6] = f2b(v3.z); u1[7] = f2b(v3.w);
            *(ushort8*)&As[a_row][a_kq]     = u0;
            *(ushort8*)&As[a_row][a_kq + 8] = u1;
        }
        {
            // B: each thread stages 16 k-values (two ushort8) — full coverage
            const ushort_t* wp = WT + (size_t)(col0 + a_row) * K + (k0 + a_kq);
            *(ushort8*)&Bs[a_row][a_kq]     = *(const ushort8*)(wp);
            *(ushort8*)&Bs[a_row][a_kq + 8] = *(const ushort8*)(wp + 8);
        }
        __syncthreads();

        short8v a[4], b[4];
#pragma unroll
        for (int mb = 0; mb < 4; ++mb)
            a[mb] = *(const short8v*)&As[wm + mb * 16 + m16][kof];
#pragma unroll
        for (int nb = 0; nb < 4; ++nb)
            b[nb] = *(const short8v*)&Bs[wn + nb * 16 + m16][kof];
#pragma unroll
        for (int mb = 0; mb < 4; ++mb)
#pragma unroll
            for (int nb = 0; nb < 4; ++nb)
                acc[mb][nb] = __builtin_amdgcn_mfma_f32_16x16x32_bf16(
                    a[mb], b[nb], acc[mb][nb], 0, 0, 0);
        __syncthreads();
    }

    const int r_base = row0 + wm + (lane >> 4) * 4;
#pragma unroll
    for (int nb = 0; nb < 4; ++nb) {
        const int col = col0 + wn + nb * 16 + m16;
        const float bv = bias[col];
#pragma unroll
        for (int mb = 0; mb < 4; ++mb) {
#pragma unroll
            for (int r = 0; r < 4; ++r) {
                const int row = r_base + mb * 16 + r;
                const float v = acc[mb][nb][r] + bv;
                if (col < 192) {
                    qb[(size_t)row * 192 + col] = f2b(v);
                } else if (col < 576) {
                    const int u = col - 192, h = u >> 5, c = u & 31;
                    if (c < 16) kbt[(size_t)row * 192 + h * 16 + c] = f2b(v);
                    else        vbt[(size_t)row * 192 + h * 16 + (c - 16)] = f2b(v);
                } else {
                    praw[(size_t)row * 576 + (col - 576)] = v;
                }
            }
        }
    }
}

// ---------------------------------------------------------------------------
// z-projection GEMM: zph[(N*K)][48 bf16] = z[.][128] @ Wcat + bcat.
// B from pre-transposed WcatT[64][128] (rows>=44 zero).
// ---------------------------------------------------------------------------
__global__ __launch_bounds__(256) void gemm_zproj(
    const float* __restrict__ Z, const ushort_t* __restrict__ WcT,
    const float* __restrict__ bc, ushort_t* __restrict__ zph)
{
    __shared__ ushort_t As[64][40];
    __shared__ ushort_t Bs[64][40];

    const int tid  = threadIdx.x;
    const int row0 = blockIdx.x * 64;

    const int wave = tid >> 6;
    const int lane = tid & 63;
    const int wm = (wave >> 1) * 32;
    const int wn = (wave & 1) * 32;
    const int m16 = lane & 15;
    const int kof = (lane >> 4) * 8;

    const int a_row = tid >> 2;
    const int a_kq  = (tid & 3) * 8;

    f32x4 acc[2][2];
#pragma unroll
    for (int i = 0; i < 2; ++i)
#pragma unroll
        for (int j = 0; j < 2; ++j) acc[i][j] = (f32x4)0.0f;

    for (int k0 = 0; k0 < 128; k0 += 32) {
        {
            const float* ap = Z + (size_t)(row0 + a_row) * 128 + (k0 + a_kq);
            float4 v0 = *(const float4*)(ap);
            float4 v1 = *(const float4*)(ap + 4);
            ushort8 u;
            u[0] = f2b(v0.x); u[1] = f2b(v0.y); u[2] = f2b(v0.z); u[3] = f2b(v0.w);
            u[4] = f2b(v1.x); u[5] = f2b(v1.y); u[6] = f2b(v1.z); u[7] = f2b(v1.w);
            *(ushort8*)&As[a_row][a_kq] = u;
        }
        *(ushort8*)&Bs[a_row][a_kq] =
            *(const ushort8*)(WcT + (size_t)a_row * 128 + (k0 + a_kq));
        __syncthreads();

        short8v a[2], b[2];
#pragma unroll
        for (int mb = 0; mb < 2; ++mb)
            a[mb] = *(const short8v*)&As[wm + mb * 16 + m16][kof];
#pragma unroll
        for (int nb = 0; nb < 2; ++nb)
            b[nb] = *(const short8v*)&Bs[wn + nb * 16 + m16][kof];
#pragma unroll
        for (int mb = 0; mb < 2; ++mb)
#pragma unroll
            for (int nb = 0; nb < 2; ++nb)
                acc[mb][nb] = __builtin_amdgcn_mfma_f32_16x16x32_bf16(
                    a[mb], b[nb], acc[mb][nb], 0, 0, 0);
        __syncthreads();
    }

    const int r_base = row0 + wm + (lane >> 4) * 4;
#pragma unroll
    for (int nb = 0; nb < 2; ++nb) {
        const int col = wn + nb * 16 + m16;
        if (col >= 44) continue;
        const float bv = bc[col];
#pragma unroll
        for (int mb = 0; mb < 2; ++mb) {
#pragma unroll
            for (int r = 0; r < 4; ++r) {
                zph[(size_t)(r_base + mb * 16 + r) * 48 + col] = f2b(acc[mb][nb][r] + bv);
            }
        }
    }
}

// ---------------------------------------------------------------------------
// out-GEMM: A bf16 (catb), B from WoutT[384][960] bf16, 64x64 tile, swizzle.
// ---------------------------------------------------------------------------
__global__ __launch_bounds__(256) void gemm_out(
    const ushort_t* __restrict__ A, const ushort_t* __restrict__ WT,
    const float* __restrict__ bias, float* __restrict__ C)
{
    __shared__ ushort_t As[64][40];
    __shared__ ushort_t Bs[64][40];

    const int tid  = threadIdx.x;
    const int ncol = 6;                        // 384/64
    const int id   = blockIdx.x;
    const int xcd  = id & 7;
    const int qq   = id >> 3;
    const int row0 = ((qq / ncol) * 8 + xcd) * 64;
    const int col0 = (qq % ncol) * 64;
    const int K = 960, P = 384;

    const int wave = tid >> 6;
    const int lane = tid & 63;
    const int wm = (wave >> 1) * 32;
    const int wn = (wave & 1) * 32;
    const int m16 = lane & 15;
    const int kof = (lane >> 4) * 8;

    const int a_row = tid >> 2;
    const int a_kq  = (tid & 3) * 8;

    f32x4 acc[2][2];
#pragma unroll
    for (int i = 0; i < 2; ++i)
#pragma unroll
        for (int j = 0; j < 2; ++j) acc[i][j] = (f32x4)0.0f;

    for (int k0 = 0; k0 < K; k0 += 32) {
        *(ushort8*)&As[a_row][a_kq] =
            *(const ushort8*)(A + (size_t)(row0 + a_row) * K + (k0 + a_kq));
        *(ushort8*)&Bs[a_row][a_kq] =
            *(const ushort8*)(WT + (size_t)(col0 + a_row) * K + (k0 + a_kq));
        __syncthreads();

        short8v a[2], b[2];
#pragma unroll
        for (int mb = 0; mb < 2; ++mb)
            a[mb] = *(const short8v*)&As[wm + mb * 16 + m16][kof];
#pragma unroll
        for (int nb = 0; nb < 2; ++nb)
            b[nb] = *(const short8v*)&Bs[wn + nb * 16 + m16][kof];
#pragma unroll
        for (int mb = 0; mb < 2; ++mb)
#pragma unroll
            for (int nb = 0; nb < 2; ++nb)
                acc[mb][nb] = __builtin_amdgcn_mfma_f32_16x16x32_bf16(
                    a[mb], b[nb], acc[mb][nb], 0, 0, 0);
        __syncthreads();
    }

    const int r_base = row0 + wm + (lane >> 4) * 4;
#pragma unroll
    for (int nb = 0; nb < 2; ++nb) {
        const int col = col0 + wn + nb * 16 + m16;
        const float bv = bias[col];
#pragma unroll
        for (int mb = 0; mb < 2; ++mb) {
#pragma unroll
            for (int r = 0; r < 4; ++r) {
                C[(size_t)(r_base + mb * 16 + r) * P + col] = acc[mb][nb][r] + bv;
            }
        }
    }
}

// ---------------------------------------------------------------------------
// prep_pts: points only (q_pts fp32, kpt fp32, vpt bf16). 192 tasks/node.
// praw row: [qpX(48)|qpY(48)|qpZ(48) | kvX(144)|kvY(144)|kvZ(144)]
// ---------------------------------------------------------------------------
__global__ void prep_pts(const float* __restrict__ praw,
                         const float* __restrict__ rot,
                         const float* __restrict__ trans,
                         float* __restrict__ q_pts,
                         float* __restrict__ kpt,
                         ushort_t* __restrict__ vpt)
{
    int t = blockIdx.x * 256 + threadIdx.x;
    if (t >= N_NODES * 192) return;
    const int n = t / 192;
    const int m = t % 192;
    const float* row = praw + (size_t)n * 576;
    const float* R  = rot + n * 9;
    const float* tr = trans + n * 3;
    float X, Y, Z;
    if (m < 48) { X = row[m];       Y = row[48 + m];   Z = row[96 + m]; }
    else { const int pt = m - 48;
           X = row[144 + pt];  Y = row[288 + pt]; Z = row[432 + pt]; }
    const float gx = R[0] * X + R[1] * Y + R[2] * Z + tr[0];
    const float gy = R[3] * X + R[4] * Y + R[5] * Z + tr[1];
    const float gz = R[6] * X + R[7] * Y + R[8] * Z + tr[2];
    if (m < 48) {
        const int h = m >> 2, p = m & 3;
        float* dst = q_pts + (size_t)n * 144 + h * 12 + p * 3;
        dst[0] = gx; dst[1] = gy; dst[2] = gz;
    } else {
        const int pt = m - 48, h = pt / 12, p = pt % 12;
        if (p < 4) {
            float* dst = kpt + (size_t)n * 144 + h * 12 + p * 3;
            dst[0] = gx; dst[1] = gy; dst[2] = gz;
        } else {
            ushort_t* dst = vpt + (size_t)n * 288 + h * 24 + (p - 4) * 3;
            dst[0] = f2b(gx); dst[1] = f2b(gy); dst[2] = f2b(gz);
        }
    }
}

// ---------------------------------------------------------------------------
// attention (de-staged): one block (256 thr) per node. qb bf16 in.
// ---------------------------------------------------------------------------
__global__ __launch_bounds__(256, 8) void attn_kernel(
    const ushort_t* __restrict__ qb,       // N x 192 bf16
    const ushort_t* __restrict__ kbt,      // N x 192 bf16
    const ushort_t* __restrict__ vbt,      // N x 192 bf16
    const float* __restrict__ q_pts,       // N x 144 f32
    const float* __restrict__ kpt,         // N x 144 f32
    const ushort_t* __restrict__ vpt,      // N x 288 bf16
    const ushort_t* __restrict__ zph,      // (N*K) x 48 bf16 (44 valid)
    const int*   __restrict__ eidx,
    const float* __restrict__ mask,
    const float* __restrict__ rot,
    const float* __restrict__ trans,
    const float* __restrict__ head_weights,
    ushort_t* __restrict__ catb)           // N x 960 bf16
{
    const int n   = blockIdx.x;
    const int tid = threadIdx.x;

    __shared__ ushort_t zp[32][48];     // 3072B
    __shared__ float q_s[192];
    __shared__ float qp_s[144];
    __shared__ float a_s[12][33];
    __shared__ float opt[288];          // h*24 + p*3 + x
    __shared__ int   idx_s[32];
    __shared__ float madd_s[32];
    __shared__ float R_s[9];
    __shared__ float t_s[3];
    __shared__ float hw_s[12];

    // ---- phase 0: stage reused data ----
    for (int i = tid; i < 192; i += 256) q_s[i]  = b2f(qb[(size_t)n * 192 + i]);
    for (int i = tid; i < 144; i += 256) qp_s[i] = q_pts[(size_t)n * 144 + i];
    if (tid < 32) {
        const int ix = eidx[n * 32 + tid];
        idx_s[tid]  = ix;
        madd_s[tid] = 100000.0f * (mask[ix] - 1.0f);
    }
    if (tid >= 32 && tid < 41) R_s[tid - 32]  = rot[n * 9 + (tid - 32)];
    if (tid >= 41 && tid < 44) t_s[tid - 41]  = trans[n * 3 + (tid - 41)];
    if (tid >= 44 && tid < 56) {
        float x = head_weights[tid - 44];
        hw_s[tid - 44] = log1pf(__expf(x)) * 0.13608276348795434f; // softplus*sqrt(1/54)
    }
    if (tid < 192) {                    // zp: 32 rows x 6 chunks of 8 ushorts
        const int r = tid / 6, sg = tid % 6;
        *(ushort8*)&zp[r][sg * 8] =
            *(const ushort8*)(zph + ((size_t)n * 32 + r) * 48 + sg * 8);
    }
    __syncthreads();

    // ---- phase 1: logits, direct gather ----
    for (int t = tid; t < 384; t += 256) {
        const int h = t >> 5, j = t & 31;
        const int ix = idx_s[j];
        const ushort_t* kr = kbt + (size_t)ix * 192 + h * 16;
        ushort8 k0 = *(const ushort8*)(kr);
        ushort8 k1 = *(const ushort8*)(kr + 8);
        const float* kpr = kpt + (size_t)ix * 144 + h * 12;
        float4 p0 = *(const float4*)(kpr);
        float4 p1 = *(const float4*)(kpr + 4);
        float4 p2 = *(const float4*)(kpr + 8);

        const float* qh = q_s + h * 16;
        float dot = 0.0f;
#pragma unroll
        for (int c = 0; c < 8; ++c) dot += qh[c] * b2f(k0[c]);
#pragma unroll
        for (int c = 0; c < 8; ++c) dot += qh[8 + c] * b2f(k1[c]);

        const float* qp = qp_s + h * 12;
        float d, pt = 0.0f;
        d = qp[0]  - p0.x; pt += d * d;  d = qp[1]  - p0.y; pt += d * d;
        d = qp[2]  - p0.z; pt += d * d;  d = qp[3]  - p0.w; pt += d * d;
        d = qp[4]  - p1.x; pt += d * d;  d = qp[5]  - p1.y; pt += d * d;
        d = qp[6]  - p1.z; pt += d * d;  d = qp[7]  - p1.w; pt += d * d;
        d = qp[8]  - p2.x; pt += d * d;  d = qp[9]  - p2.y; pt += d * d;
        d = qp[10] - p2.z; pt += d * d;  d = qp[11] - p2.w; pt += d * d;

        a_s[h][j] = 0.14433756729740643f * dot
                  + 0.5773502691896258f * b2f(zp[j][h])
                  - 0.5f * hw_s[h] * pt
                  + madd_s[j];
    }
    __syncthreads();

    // ---- phase 2: parallel softmax (96 threads, 8-lane shuffle groups) ----
    if (tid < 96) {
        const int h = tid >> 3, g = tid & 7;
        float a0 = a_s[h][g * 4 + 0], a1 = a_s[h][g * 4 + 1];
        float a2 = a_s[h][g * 4 + 2], a3 = a_s[h][g * 4 + 3];
        float m = fmaxf(fmaxf(a0, a1), fmaxf(a2, a3));
        m = fmaxf(m, __shfl_xor(m, 1)); m = fmaxf(m, __shfl_xor(m, 2));
        m = fmaxf(m, __shfl_xor(m, 4));
        float e0 = __expf(a0 - m), e1 = __expf(a1 - m);
        float e2 = __expf(a2 - m), e3 = __expf(a3 - m);
        float s = e0 + e1 + e2 + e3;
        s += __shfl_xor(s, 1); s += __shfl_xor(s, 2); s += __shfl_xor(s, 4);
        const float inv = 1.0f / s;
        a_s[h][g * 4 + 0] = e0 * inv; a_s[h][g * 4 + 1] = e1 * inv;
        a_s[h][g * 4 + 2] = e2 * inv; a_s[h][g * 4 + 3] = e3 * inv;
    }
    __syncthreads();

    // ---- phase 3: weighted sums, wave-coalesced direct reads ----
    ushort_t* catn = catb + (size_t)n * 960;
    if (tid < 48) {                      // o: (h, c-quad)
        const int h = tid >> 2, cq = tid & 3;
        const ushort_t* base = vbt + h * 16 + cq * 4;
        float s0 = 0, s1 = 0, s2 = 0, s3 = 0;
#pragma unroll 8
        for (int j = 0; j < 32; ++j) {
            const int ix = idx_s[j];
            const float aj = a_s[h][j];
            ushort4v v = *(const ushort4v*)(base + (size_t)ix * 192);
            s0 += aj * b2f(v[0]); s1 += aj * b2f(v[1]);
            s2 += aj * b2f(v[2]); s3 += aj * b2f(v[3]);
        }
        ushort4v o = { f2b(s0), f2b(s1), f2b(s2), f2b(s3) };
        *(ushort4v*)&catn[h * 16 + cq * 4] = o;
    } else if (tid < 120) {              // o_pt: (h, quad of 24)
        const int u = tid - 48;
        const int h = u / 6, rq = u % 6;
        const ushort_t* base = vpt + h * 24 + rq * 4;
        float s0 = 0, s1 = 0, s2 = 0, s3 = 0;
#pragma unroll 8
        for (int j = 0; j < 32; ++j) {
            const int ix = idx_s[j];
            const float aj = a_s[h][j];
            ushort4v v = *(const ushort4v*)(base + (size_t)ix * 288);
            s0 += aj * b2f(v[0]); s1 += aj * b2f(v[1]);
            s2 += aj * b2f(v[2]); s3 += aj * b2f(v[3]);
        }
        float* od = opt + h * 24 + rq * 4;
        od[0] = s0; od[1] = s1; od[2] = s2; od[3] = s3;
    } else if (tid < 216) {              // o_pair: (h, c-quad of 32)
        const int u = tid - 120;
        const int h = u >> 3, cq = u & 7;
        float s0 = 0, s1 = 0, s2 = 0, s3 = 0;
#pragma unroll 8
        for (int j = 0; j < 32; ++j) {
            const float aj = a_s[h][j];
            ushort4v zv = *(const ushort4v*)&zp[j][12 + cq * 4];
            s0 += aj * b2f(zv[0]); s1 += aj * b2f(zv[1]);
            s2 += aj * b2f(zv[2]); s3 += aj * b2f(zv[3]);
        }
        ushort4v o = { f2b(s0), f2b(s1), f2b(s2), f2b(s3) };
        *(ushort4v*)&catn[576 + h * 32 + cq * 4] = o;
    }
    __syncthreads();

    // ---- phase 4: rotate back + norms ----
    if (tid < 96) {
        const int h = tid >> 3, p = tid & 7;
        const float* ob = opt + h * 24 + p * 3;
        float gx = ob[0] - t_s[0];
        float gy = ob[1] - t_s[1];
        float gz = ob[2] - t_s[2];
        float lx = R_s[0] * gx + R_s[3] * gy + R_s[6] * gz;
        float ly = R_s[1] * gx + R_s[4] * gy + R_s[7] * gz;
        float lz = R_s[2] * gx + R_s[5] * gy + R_s[8] * gz;
        const int hp = h * 8 + p;
        catn[192 + hp] = f2b(lx);
        catn[288 + hp] = f2b(ly);
        catn[384 + hp] = f2b(lz);
        catn[480 + hp] = f2b(sqrtf(lx * lx + ly * ly + lz * lz + 1e-8f));
    }
}

// ---------------------------------------------------------------------------
extern "C" void kernel_launch(void* const* d_in, const int* in_sizes, int n_in,
                              void* d_out, int out_size, void* d_ws, size_t ws_size,
                              hipStream_t stream)
{
    const float* s     = (const float*)d_in[0];
    const float* z     = (const float*)d_in[1];
    const int*   eidx  = (const int*)  d_in[2];
    const float* rot   = (const float*)d_in[3];
    const float* trans = (const float*)d_in[4];
    const float* mask  = (const float*)d_in[5];
    const float* w_q   = (const float*)d_in[6];
    const float* b_q   = (const float*)d_in[7];
    const float* w_kv  = (const float*)d_in[8];
    const float* b_kv  = (const float*)d_in[9];
    const float* w_qp  = (const float*)d_in[10];
    const float* b_qp  = (const float*)d_in[11];
    const float* w_kvp = (const float*)d_in[12];
    const float* b_kvp = (const float*)d_in[13];
    const float* w_b   = (const float*)d_in[14];
    const float* b_b   = (const float*)d_in[15];
    const float* w_dz  = (const float*)d_in[16];
    const float* b_dz  = (const float*)d_in[17];
    const float* hw    = (const float*)d_in[18];
    const float* w_out = (const float*)d_in[19];
    const float* b_out = (const float*)d_in[20];
    float* out = (float*)d_out;

    float* ws = (float*)d_ws;
    size_t off = 0;
    ushort_t* qb    = (ushort_t*)(ws + off); off += (size_t)N_NODES * 96;   // 192 bf16
    ushort_t* kbt   = (ushort_t*)(ws + off); off += (size_t)N_NODES * 96;
    ushort_t* vbt   = (ushort_t*)(ws + off); off += (size_t)N_NODES * 96;
    float* praw     = ws + off;              off += (size_t)N_NODES * 576;
    float* q_pts    = ws + off;              off += (size_t)N_NODES * 144;
    float* kpt      = ws + off;              off += (size_t)N_NODES * 144;
    ushort_t* vpt   = (ushort_t*)(ws + off); off += (size_t)N_NODES * 144;  // 288 bf16
    ushort_t* zph   = (ushort_t*)(ws + off); off += (size_t)N_NODES * KNN * 24; // 48 bf16
    ushort_t* catb  = (ushort_t*)(ws + off); off += (size_t)N_NODES * 480;      // 960 bf16
    ushort_t* WallT = (ushort_t*)(ws + off); off += N_WALLT / 2;
    float* ball     = ws + off;              off += 1152;
    ushort_t* WcatT = (ushort_t*)(ws + off); off += N_WCATT / 2;
    float* bcat     = ws + off;              off += 44;
    ushort_t* WoutT = (ushort_t*)(ws + off); off += N_WOUTT / 2;

    // 1) all weight tables (one launch)
    build_weights<<<(BW_TOTAL + 255) / 256, 256, 0, stream>>>(
        w_q, b_q, w_kv, b_kv, w_qp, b_qp, w_kvp, b_kvp,
        w_b, b_b, w_dz, b_dz, w_out, WallT, ball, WcatT, bcat, WoutT);

    // 2) s-projection with split epilogue (qb | kbt/vbt | praw)
    gemm_sproj<<<(N_NODES / 128) * 9, 256, 0, stream>>>(
        s, WallT, ball, qb, kbt, vbt, praw);

    // 3) z-projection -> bf16 zph (streaming)
    gemm_zproj<<<(N_NODES * KNN) / 64, 256, 0, stream>>>(z, WcatT, bcat, zph);

    // 4) point transforms
    prep_pts<<<(N_NODES * 192 + 255) / 256, 256, 0, stream>>>(
        praw, rot, trans, q_pts, kpt, vpt);

    // 5) attention
    attn_kernel<<<N_NODES, 256, 0, stream>>>(
        qb, kbt, vbt, q_pts, kpt, vpt, zph, eidx, mask, rot, trans, hw, catb);

    // 6) output projection
    gemm_out<<<(N_NODES / 64) * 6, 256, 0, stream>>>(catb, WoutT, b_out, out);
}